// Round 15
// baseline (355.136 us; speedup 1.0000x reference)
//
#include <hip/hip_runtime.h>
#include <hip/hip_bf16.h>

#define B_   4
#define TQ_  2048
#define TKV_ 2048
#define DM_  1024
#define H_   16
#define DH_  64

// 1/sqrt(DK) * log2(e), folded into Wq/bq so attention exp2 needs no scaling
#define SC_FOLD 0.18033688011112042f

using f32x4  = __attribute__((ext_vector_type(4))) float;
using f32x16 = __attribute__((ext_vector_type(16))) float;
using s16x8  = __attribute__((ext_vector_type(8))) short;

static __device__ __forceinline__ unsigned short f2bf(float f) {
  union { float f; unsigned int u; } v; v.f = f;
  unsigned int r = v.u + 0x7FFFu + ((v.u >> 16) & 1u);
  return (unsigned short)(r >> 16);
}
// packed f32 pair -> 2xbf16 (RNE) in one instruction
static __device__ __forceinline__ unsigned int pk2(float a, float b) {
  unsigned int r;
  asm("v_cvt_pk_bf16_f32 %0, %1, %2" : "=v"(r) : "v"(a), "v"(b));
  return r;
}
static __device__ __forceinline__ float max3f(float a, float b, float c) {
  float r;
  asm("v_max3_f32 %0, %1, %2, %3" : "=v"(r) : "v"(a), "v"(b), "v"(c));
  return r;
}

// async global->LDS, 16B per lane; LDS dest is wave-uniform base + lane*16
#define GL16(g, l)                                                          \
  __builtin_amdgcn_global_load_lds(                                         \
      (const __attribute__((address_space(1))) unsigned int*)(g),           \
      (__attribute__((address_space(3))) unsigned int*)(l), 16, 0, 0)

// ---------------- batched transpose + cast + scale (3 weights, 1 launch) ----------------
__global__ __launch_bounds__(256) void k_transpose_cast_all(
    const float* __restrict__ Wq, unsigned short* __restrict__ WqT,
    const float* __restrict__ Wkv, unsigned short* __restrict__ WkvT,
    const float* __restrict__ Wo, unsigned short* __restrict__ WoT) {
  __shared__ float t[64][65];
  int bid = blockIdx.x;
  const float* W;
  unsigned short* WT;
  int K = 1024, N, n0, k0;
  float scale;
  if (bid < 256) {
    W = Wq; WT = WqT; N = 1024; scale = SC_FOLD;
    n0 = (bid & 15) * 64; k0 = (bid >> 4) * 64;
  } else if (bid < 768) {
    int b2 = bid - 256;
    W = Wkv; WT = WkvT; N = 2048; scale = 1.0f;
    n0 = (b2 & 31) * 64; k0 = (b2 >> 5) * 64;
  } else {
    int b2 = bid - 768;
    W = Wo; WT = WoT; N = 1024; scale = 1.0f;
    n0 = (b2 & 15) * 64; k0 = (b2 >> 4) * 64;
  }
  int tx = threadIdx.x & 63, ty = threadIdx.x >> 6;
#pragma unroll
  for (int i = 0; i < 64; i += 4)
    t[ty + i][tx] = W[(size_t)(k0 + ty + i) * N + n0 + tx];
  __syncthreads();
#pragma unroll
  for (int i = 0; i < 64; i += 4)
    WT[(size_t)(n0 + ty + i) * K + k0 + tx] = f2bf(t[tx][ty + i] * scale);
}

// ---------------- elementwise cast f32 -> bf16 ----------------
__global__ __launch_bounds__(256) void k_cast_bf16(
    const float* __restrict__ in, unsigned short* __restrict__ out, int n4) {
  for (int i = blockIdx.x * 256 + threadIdx.x; i < n4; i += gridDim.x * 256) {
    f32x4 v = *(const f32x4*)(in + (size_t)i * 4);
    unsigned long long u = (unsigned long long)pk2(v[0], v[1]) |
                           ((unsigned long long)pk2(v[2], v[3]) << 32);
    *(unsigned long long*)(out + (size_t)i * 4) = u;
  }
}

// ---------------- GEMM, 8-phase 256-row tile (T1+T2+T3+T4+T5) — unchanged R9 ----------------
template <int MODE, int BN>
__global__ __launch_bounds__(512, 2) void k_gemm8(
    const unsigned short* __restrict__ A, const unsigned short* __restrict__ BT,
    const float* __restrict__ bias, float bscale, unsigned short* __restrict__ out_a,
    unsigned short* __restrict__ out_b, float* __restrict__ out_f, int Kd) {
  constexpr int NI = BN / 64;
  constexpr int NH = NI / 2;
  __shared__ __align__(16) unsigned short As[2 * 256 * 64];
  __shared__ __align__(16) unsigned short Bs[2 * BN * 64];
  const int tid = threadIdx.x, lane = tid & 63, w = tid >> 6;
  const int wm = w >> 2, wn = w & 3;

  int nwg = gridDim.x * gridDim.y;
  int bid = blockIdx.y * gridDim.x + blockIdx.x;
  int cpx = nwg >> 3;
  int sw = (bid & 7) * cpx + (bid >> 3);
  int bx = sw % gridDim.x, by = sw / gridDim.x;
  int m0 = by * 256, n0 = bx * BN;

  const int strow = tid >> 3;
  const int sx = ((tid & 7) << 4) ^ ((strow & 7) << 4);
  const char* gA = (const char*)(A + (size_t)(m0 + strow) * Kd) + sx;
  const char* gB = (const char*)(BT + (size_t)(n0 + strow) * Kd) + sx;
  char* lA = (char*)As;
  char* lB = (char*)Bs;

#define ST_A(bf, c, k0) \
  GL16(gA + ((size_t)(c) * 64 * Kd + (size_t)(k0)) * 2, lA + (bf) * 32768 + (c) * 8192 + tid * 16)
#define ST_B(bf, c, k0) \
  GL16(gB + ((size_t)(c) * 64 * Kd + (size_t)(k0)) * 2, lB + (bf) * (BN * 128) + (c) * 8192 + tid * 16)

  f32x4 acc[8][NI];
#pragma unroll
  for (int i = 0; i < 8; ++i)
#pragma unroll
    for (int j = 0; j < NI; ++j) acc[i][j] = (f32x4){0.f, 0.f, 0.f, 0.f};

  s16x8 afr[4][2], bfr[NI][2];
  const int arow = wm * 128 + (lane & 15);
  const int brow = wn * (NI * 16) + (lane & 15);
  const int fcol = (lane >> 4) * 16;

#define RD_A(bf, r) (*(const s16x8*)(lA + (bf) * 32768 + (r) * 128 + ((fcol + _kk * 64) ^ (((r) & 7) << 4))))
#define RD_B(bf, r) (*(const s16x8*)(lB + (bf) * (BN * 128) + (r) * 128 + ((fcol + _kk * 64) ^ (((r) & 7) << 4))))

  const int nT = Kd >> 6;

  ST_B(0, 0, 0); ST_B(0, 1, 0);
  if (BN == 256) { ST_B(0, 2, 0); ST_B(0, 3, 0); }
  ST_A(0, 0, 0); ST_A(0, 2, 0);
  ST_A(0, 1, 0); ST_A(0, 3, 0);
  asm volatile("s_waitcnt vmcnt(2)" ::: "memory");
  __builtin_amdgcn_s_barrier();

#pragma unroll 1
  for (int t = 0; t < nT; ++t) {
    const int cur = t & 1, nxt = cur ^ 1;
    const int k1 = (t + 1) << 6;
    const bool st = (t + 1 < nT);

#pragma unroll
    for (int mi = 0; mi < 4; ++mi)
#pragma unroll
      for (int _kk = 0; _kk < 2; ++_kk) afr[mi][_kk] = RD_A(cur, arow + mi * 16);
#pragma unroll
    for (int ni = 0; ni < NH; ++ni)
#pragma unroll
      for (int _kk = 0; _kk < 2; ++_kk) bfr[ni][_kk] = RD_B(cur, brow + ni * 16);
    if (st) { ST_B(nxt, 0, k1); ST_B(nxt, 1, k1); }
    __builtin_amdgcn_s_barrier();
    __builtin_amdgcn_s_setprio(1);
#pragma unroll
    for (int mi = 0; mi < 4; ++mi)
#pragma unroll
      for (int ni = 0; ni < NH; ++ni)
#pragma unroll
        for (int kk = 0; kk < 2; ++kk)
          acc[mi][ni] = __builtin_amdgcn_mfma_f32_16x16x32_bf16(afr[mi][kk], bfr[ni][kk], acc[mi][ni], 0, 0, 0);
    __builtin_amdgcn_s_setprio(0);
    __builtin_amdgcn_s_barrier();

#pragma unroll
    for (int ni = NH; ni < NI; ++ni)
#pragma unroll
      for (int _kk = 0; _kk < 2; ++_kk) bfr[ni][_kk] = RD_B(cur, brow + ni * 16);
    if (st) {
      if (BN == 256) { ST_B(nxt, 2, k1); ST_B(nxt, 3, k1); }
      else           { ST_A(nxt, 0, k1); ST_A(nxt, 2, k1); }
    }
    if (st) asm volatile("s_waitcnt vmcnt(4)" ::: "memory");
    else    asm volatile("s_waitcnt vmcnt(0)" ::: "memory");
    __builtin_amdgcn_s_barrier();
    __builtin_amdgcn_s_setprio(1);
#pragma unroll
    for (int mi = 0; mi < 4; ++mi)
#pragma unroll
      for (int ni = NH; ni < NI; ++ni)
#pragma unroll
        for (int kk = 0; kk < 2; ++kk)
          acc[mi][ni] = __builtin_amdgcn_mfma_f32_16x16x32_bf16(afr[mi][kk], bfr[ni][kk], acc[mi][ni], 0, 0, 0);
    __builtin_amdgcn_s_setprio(0);
    __builtin_amdgcn_s_barrier();

#pragma unroll
    for (int mi = 0; mi < 4; ++mi)
#pragma unroll
      for (int _kk = 0; _kk < 2; ++_kk) afr[mi][_kk] = RD_A(cur, arow + (mi + 4) * 16);
    if (st) {
      if (BN == 256) { ST_A(nxt, 0, k1); ST_A(nxt, 2, k1); }
      else           { ST_A(nxt, 1, k1); ST_A(nxt, 3, k1); }
    }
    __builtin_amdgcn_s_barrier();
    __builtin_amdgcn_s_setprio(1);
#pragma unroll
    for (int mi = 0; mi < 4; ++mi)
#pragma unroll
      for (int ni = 0; ni < NH; ++ni)
#pragma unroll
        for (int kk = 0; kk < 2; ++kk)
          acc[mi + 4][ni] = __builtin_amdgcn_mfma_f32_16x16x32_bf16(afr[mi][kk], bfr[ni][kk], acc[mi + 4][ni], 0, 0, 0);
    __builtin_amdgcn_s_setprio(0);
    __builtin_amdgcn_s_barrier();

    if (st && BN == 256) { ST_A(nxt, 1, k1); ST_A(nxt, 3, k1); }
    asm volatile("s_waitcnt vmcnt(2)" ::: "memory");
    __builtin_amdgcn_s_barrier();
    __builtin_amdgcn_s_setprio(1);
#pragma unroll
    for (int mi = 0; mi < 4; ++mi)
#pragma unroll
      for (int ni = NH; ni < NI; ++ni)
#pragma unroll
        for (int kk = 0; kk < 2; ++kk)
          acc[mi + 4][ni] = __builtin_amdgcn_mfma_f32_16x16x32_bf16(afr[mi][kk], bfr[ni][kk], acc[mi + 4][ni], 0, 0, 0);
    __builtin_amdgcn_s_setprio(0);
    __builtin_amdgcn_s_barrier();
  }

#pragma unroll
  for (int mi = 0; mi < 8; ++mi) {
#pragma unroll
    for (int ni = 0; ni < NI; ++ni) {
      int col = n0 + wn * (NI * 16) + ni * 16 + (lane & 15);
      int rbase = m0 + wm * 128 + mi * 16 + (lane >> 4) * 4;
      float bv = bias[col] * bscale;
      if (MODE == 1 && col >= H_ * DH_) {
        int c2 = col - H_ * DH_;
        int h = c2 >> 6, d = c2 & 63;
        int b = rbase >> 11, tt = rbase & 2047;
        union { unsigned short h4[4]; unsigned long long u; } p;
#pragma unroll
        for (int r = 0; r < 4; ++r) p.h4[r] = f2bf(acc[mi][ni][r] + bv);
        *(unsigned long long*)(out_b + ((((size_t)b * H_ + h) * DH_ + d) * TKV_ + tt)) = p.u;
      } else {
#pragma unroll
        for (int r = 0; r < 4; ++r) {
          float v = acc[mi][ni][r] + bv;
          int m = rbase + r;
          if (MODE == 0) {
            int b = m >> 11, tt = m & 2047;
            int h = col >> 6, d = col & 63;
            out_a[(((size_t)b * H_ + h) * TQ_ + tt) * DH_ + d] = f2bf(v);
          } else if (MODE == 1) {
            int b = m >> 11, tt = m & 2047;
            int h = col >> 6, d = col & 63;
            out_a[(((size_t)b * H_ + h) * TKV_ + tt) * DH_ + d] = f2bf(v);
          } else {
            out_f[(size_t)m * DM_ + col] = v;
          }
        }
      }
    }
  }
#undef ST_A
#undef ST_B
#undef RD_A
#undef RD_B
}

// ---------------- flash attention: 8 waves share staging, 256-q block ----------------
// grid (4, 64) x 512 threads = 8 waves x 32 q-rows = 256 q/block; paired passes
// (bxp, 7-bxp) over 256-row q-tiles -> 18 staged tiles/block (uniform).
// K/V dbuf in LDS, one barrier/tile; staging amortized over 8 waves (2x R13).
// VGPR<=128 via __launch_bounds__(512,4) -> 2 blocks/CU = 16 waves/CU.
__global__ __launch_bounds__(512, 4) void k_attn(
    const unsigned short* __restrict__ Qb, const unsigned short* __restrict__ Kb,
    const unsigned short* __restrict__ Vtb, const unsigned char* __restrict__ mask,
    const int* __restrict__ cflag, unsigned short* __restrict__ Ob) {
  __shared__ __align__(16) unsigned short Kt[2][128 * 64];  // [buf][kv][d], XOR-swizzled
  __shared__ __align__(16) unsigned short Vt[2][64 * 128];  // [buf][d][kv], XOR-swizzled
  __shared__ float bias_lds[2][128];
  __shared__ float red[8][32];
  __shared__ int s_any;

  // XCD head-locality swizzle: 4 q-blocks of a head on one XCD (8 heads/XCD)
  int bid = blockIdx.y * gridDim.x + blockIdx.x;
  int r8 = bid & 7, q8 = bid >> 3;
  int bh = r8 * 8 + (q8 >> 2);
  int bx = q8 & 3;

  int b = bh >> 4, h = bh & 15;
  int tid = threadIdx.x, lane = tid & 63, w = tid >> 6;
  int hi = lane >> 5, l31 = lane & 31, l7 = lane & 7;
  const unsigned short* Qp = Qb + (size_t)bh * TQ_ * DH_;
  const char* Kp = (const char*)(Kb + (size_t)bh * TKV_ * DH_);
  const char* Vp = (const char*)(Vtb + (size_t)bh * DH_ * TKV_);
  const unsigned char* mp = mask + (size_t)b * TKV_;
  int causal = cflag[0];

  // staging (512 threads): K 128 rows x 128B (2x16B/thr), V 64 rows x 256B (2x16B/thr)
  int st_kr = tid >> 2;            // 0..127
  int st_kc = (tid & 3) * 16;      // 0,16,32,48
  int st_vr = tid >> 3;            // 0..63
  int st_vc = (tid & 7) * 16;      // 0..112
  s16x8 pKr[2], pVr[2];

#define LOAD_KV(kv0)                                                          \
  {                                                                           \
    pKr[0] = *(const s16x8*)(Kp + ((size_t)((kv0) + st_kr) * 128 + st_kc));   \
    pKr[1] = *(const s16x8*)(Kp + ((size_t)((kv0) + st_kr) * 128 + st_kc + 64)); \
    pVr[0] = *(const s16x8*)(Vp + (((size_t)st_vr * TKV_ + (kv0)) * 2 + st_vc)); \
    pVr[1] = *(const s16x8*)(Vp + (((size_t)st_vr * TKV_ + (kv0)) * 2 + st_vc + 128)); \
  }
#define WRITE_KV(bufi)                                                        \
  {                                                                           \
    char* kb_ = (char*)&Kt[bufi][0];                                          \
    char* vb_ = (char*)&Vt[bufi][0];                                          \
    *(s16x8*)(kb_ + st_kr * 128 + (st_kc ^ ((st_kr & 7) << 4))) = pKr[0];     \
    *(s16x8*)(kb_ + st_kr * 128 + ((st_kc + 64) ^ ((st_kr & 7) << 4))) = pKr[1]; \
    *(s16x8*)(vb_ + st_vr * 256 + (st_vc ^ ((st_vr & 7) << 4))) = pVr[0];     \
    *(s16x8*)(vb_ + st_vr * 256 + ((st_vc + 128) ^ ((st_vr & 7) << 4))) = pVr[1]; \
  }

  if (tid == 0) s_any = 0;
  __syncthreads();
  {
    int any = 0;
    for (int i = tid; i < TKV_; i += 512) any |= mp[i];
    if (any) s_any = 1;
  }
  __syncthreads();
  const int has_mask = s_any;

#pragma unroll 1
  for (int pass = 0; pass < 2; ++pass) {
    int qb = (pass ? (7 - bx) : bx) * 256;
    int qw = qb + w * 32;
    int qrow = qw + l31;

    s16x8 bQ[4];
#pragma unroll
    for (int kk = 0; kk < 4; ++kk)
      bQ[kk] = *(const s16x8*)(Qp + (size_t)qrow * DH_ + kk * 16 + hi * 8);

    f32x16 accO[2];
#pragma unroll
    for (int i = 0; i < 16; ++i) { accO[0][i] = 0.f; accO[1][i] = 0.f; }
    float m_run = -INFINITY, l_run = 0.f;

    int nT = (causal ? (qb + 256) : TKV_) >> 7;

    // prologue: stage tile 0 into buf 0
    LOAD_KV(0);
    WRITE_KV(0);
    if (has_mask && tid < 128) bias_lds[0][tid] = mp[tid] ? -1e30f : 0.0f;
    __syncthreads();

#pragma unroll 1
    for (int it = 0; it < nT; ++it) {
      int kv0 = it << 7;
      int cur = it & 1, nxt = cur ^ 1;
      if (it + 1 < nT) LOAD_KV(kv0 + 128);  // issue next-tile loads (T14)

      char* kbase = (char*)&Kt[cur][0];
      char* vbase = (char*)&Vt[cur][0];

      // wave-uniform active sub-tile count (32-kv granularity)
      int nact = 4;
      if (causal) {
        int rem = qw + 31 - kv0;
        nact = rem < 0 ? 0 : ((rem >> 5) + 1);
        if (nact > 4) nact = 4;
      }

      if (nact > 0) {
        f32x16 sT[4];
        __builtin_amdgcn_s_setprio(1);
#pragma unroll
        for (int s = 0; s < 4; ++s) {
          if (s < nact) {
#pragma unroll
            for (int i = 0; i < 16; ++i) sT[s][i] = 0.f;
#pragma unroll
            for (int kk = 0; kk < 4; ++kk) {
              s16x8 aK = *(const s16x8*)(kbase + (s * 32 + l31) * 128 +
                                         ((kk * 32 + hi * 16) ^ (l7 << 4)));
              sT[s] = __builtin_amdgcn_mfma_f32_32x32x16_bf16(aK, bQ[kk], sT[s], 0, 0, 0);
            }
          }
        }
        __builtin_amdgcn_s_setprio(0);

        // masks + row-max over active sub-tiles (4 parallel accumulators)
        float a0 = -INFINITY, a1 = -INFINITY, a2 = -INFINITY, a3 = -INFINITY;
#pragma unroll
        for (int s = 0; s < 4; ++s) {
          if (s < nact) {
            int diag_s = causal && (kv0 + s * 32 + 31 > qw);  // wave-uniform
            if (diag_s || has_mask) {
#pragma unroll
              for (int r = 0; r < 16; ++r) {
                int kvloc = s * 32 + (r & 3) + 8 * (r >> 2) + 4 * hi;
                float sv = sT[s][r];
                if (has_mask) sv += bias_lds[cur][kvloc];
                if (diag_s && (kv0 + kvloc) > qrow) sv = -1e30f;
                sT[s][r] = sv;
              }
            }
#pragma unroll
            for (int r = 0; r < 16; r += 4) {
              a0 = fmaxf(a0, sT[s][r + 0]); a1 = fmaxf(a1, sT[s][r + 1]);
              a2 = fmaxf(a2, sT[s][r + 2]); a3 = fmaxf(a3, sT[s][r + 3]);
            }
          }
        }
        float mx = max3f(max3f(a0, a1, a2), a3, -3.0e30f);
        mx = fmaxf(mx, __shfl_xor(mx, 32));

        // T13 defer-rescale
        if (!__all(mx - m_run <= 8.0f)) {
          float mnew = fmaxf(m_run, mx);
          float sc_o = exp2f(m_run - mnew);
          m_run = mnew;
          l_run *= sc_o;
          red[w][l31] = sc_o;
#pragma unroll
          for (int r = 0; r < 16; ++r) {
            float f = red[w][(r & 3) + 8 * (r >> 2) + 4 * hi];
            accO[0][r] *= f;
            accO[1][r] *= f;
          }
        }

        // exp + 4-way parallel partial sums (active sub-tiles only)
        float s0acc = 0.f, s1acc = 0.f, s2acc = 0.f, s3acc = 0.f;
#pragma unroll
        for (int s = 0; s < 4; ++s) {
          if (s < nact) {
#pragma unroll
            for (int r = 0; r < 16; r += 4) {
              float p0 = exp2f(sT[s][r + 0] - m_run);
              float p1 = exp2f(sT[s][r + 1] - m_run);
              float p2 = exp2f(sT[s][r + 2] - m_run);
              float p3 = exp2f(sT[s][r + 3] - m_run);
              sT[s][r + 0] = p0; sT[s][r + 1] = p1;
              sT[s][r + 2] = p2; sT[s][r + 3] = p3;
              s0acc += p0; s1acc += p1; s2acc += p2; s3acc += p3;
            }
          }
        }
        float ls = (s0acc + s1acc) + (s2acc + s3acc);
        ls += __shfl_xor(ls, 32);
        l_run += ls;

        // P -> A-frag via cvt_pk + permlane32_swap (T12) + PV
#pragma unroll
        for (int c = 0; c < 8; ++c) {
          if ((c >> 1) < nact) {
            int s = c >> 1, kk = c & 1;
            unsigned int x0 = pk2(sT[s][8 * kk + 0], sT[s][8 * kk + 1]);
            unsigned int y0 = pk2(sT[s][8 * kk + 2], sT[s][8 * kk + 3]);
            unsigned int x1 = pk2(sT[s][8 * kk + 4], sT[s][8 * kk + 5]);
            unsigned int y1 = pk2(sT[s][8 * kk + 6], sT[s][8 * kk + 7]);
            asm("v_permlane32_swap_b32 %0, %1" : "+v"(x0), "+v"(x1));
            asm("v_permlane32_swap_b32 %0, %1" : "+v"(y0), "+v"(y1));
            union { unsigned int u[4]; s16x8 v; } pf;
            pf.u[0] = x0;
            pf.u[1] = y0;
            pf.u[2] = x1;
            pf.u[3] = y1;
            __builtin_amdgcn_s_setprio(1);
#pragma unroll
            for (int dt = 0; dt < 2; ++dt) {
              s16x8 vf = *(const s16x8*)(vbase + (dt * 32 + l31) * 256 +
                                         ((c * 32 + hi * 16) ^ (l7 << 4)));
              accO[dt] = __builtin_amdgcn_mfma_f32_32x32x16_bf16(pf.v, vf, accO[dt], 0, 0, 0);
            }
            __builtin_amdgcn_s_setprio(0);
          }
        }
      }

      // write next tile into the other buffer, then ONE barrier (both hazards)
      if (it + 1 < nT) {
        WRITE_KV(nxt);
        if (has_mask && tid < 128) bias_lds[nxt][tid] = mp[kv0 + 128 + tid] ? -1e30f : 0.0f;
      }
      __syncthreads();
    }

    // epilogue
    red[w][l31] = 1.0f / l_run;
#pragma unroll
    for (int r = 0; r < 16; ++r) {
      int R = (r & 3) + 8 * (r >> 2) + 4 * hi;
      float f = red[w][R];
      int qg = qw + R;
      size_t base = ((size_t)b * TQ_ + qg) * DM_ + h * DH_ + l31;
      Ob[base] = f2bf(accO[0][r] * f);
      Ob[base + 32] = f2bf(accO[1][r] * f);
    }
  }
#undef LOAD_KV
#undef WRITE_KV
}

extern "C" void kernel_launch(void* const* d_in, const int* in_sizes, int n_in,
                              void* d_out, int out_size, void* d_ws, size_t ws_size,
                              hipStream_t stream) {
  const float* xq  = (const float*)d_in[0];
  const float* xkv = (const float*)d_in[1];
  const unsigned char* mask = (const unsigned char*)d_in[2];
  const float* Wq  = (const float*)d_in[3];
  const float* bq  = (const float*)d_in[4];
  const float* Wkv = (const float*)d_in[5];
  const float* bkv = (const float*)d_in[6];
  const float* Wo  = (const float*)d_in[7];
  const float* bo  = (const float*)d_in[8];
  const int* cflag = (const int*)d_in[9];
  float* out = (float*)d_out;

  char* ws = (char*)d_ws;
  unsigned short* WqT  = (unsigned short*)(ws);                       // 2 MiB
  unsigned short* WkvT = (unsigned short*)(ws + ((size_t)2 << 20));   // 4 MiB
  unsigned short* WoT  = (unsigned short*)(ws + ((size_t)6 << 20));   // 2 MiB
  unsigned short* Qb   = (unsigned short*)(ws + ((size_t)8 << 20));   // [B,H,TQ,64]
  unsigned short* Kb   = (unsigned short*)(ws + ((size_t)24 << 20));  // [B,H,TKV,64]
  unsigned short* Vb   = (unsigned short*)(ws + ((size_t)40 << 20));  // [B,H,64,TKV]
  unsigned short* Xr   = (unsigned short*)(ws + ((size_t)56 << 20));  // Aq -> Akv -> Ob
  unsigned short* Ob   = Xr;

  k_transpose_cast_all<<<1024, 256, 0, stream>>>(Wq, WqT, Wkv, WkvT, Wo, WoT);

  k_cast_bf16<<<2048, 256, 0, stream>>>(xq, Xr, B_ * TQ_ * DM_ / 4);
  k_gemm8<0, 128><<<dim3(8, 32), 512, 0, stream>>>(Xr, WqT, bq, SC_FOLD, Qb, nullptr, nullptr, 1024);

  k_cast_bf16<<<2048, 256, 0, stream>>>(xkv, Xr, B_ * TKV_ * DM_ / 4);
  k_gemm8<1, 256><<<dim3(8, 32), 512, 0, stream>>>(Xr, WkvT, bkv, 1.0f, Kb, Vb, nullptr, 1024);

  k_attn<<<dim3(4, B_ * H_), 512, 0, stream>>>(Qb, Kb, Vb, mask, cflag, Ob);

  k_gemm8<2, 128><<<dim3(8, 32), 512, 0, stream>>>(Ob, WoT, bo, 1.0f, nullptr, nullptr, out, 1024);
}

// Round 16
// 192.022 us; speedup vs baseline: 1.8495x; 1.8495x over previous
//
#include <hip/hip_runtime.h>
#include <hip/hip_bf16.h>

#define B_   4
#define TQ_  2048
#define TKV_ 2048
#define DM_  1024
#define H_   16
#define DH_  64

// 1/sqrt(DK) * log2(e), folded into Wq/bq so attention exp2 needs no scaling
#define SC_FOLD 0.18033688011112042f

using f32x4  = __attribute__((ext_vector_type(4))) float;
using f32x16 = __attribute__((ext_vector_type(16))) float;
using s16x8  = __attribute__((ext_vector_type(8))) short;

static __device__ __forceinline__ unsigned short f2bf(float f) {
  union { float f; unsigned int u; } v; v.f = f;
  unsigned int r = v.u + 0x7FFFu + ((v.u >> 16) & 1u);
  return (unsigned short)(r >> 16);
}
// packed f32 pair -> 2xbf16 (RNE) in one instruction
static __device__ __forceinline__ unsigned int pk2(float a, float b) {
  unsigned int r;
  asm("v_cvt_pk_bf16_f32 %0, %1, %2" : "=v"(r) : "v"(a), "v"(b));
  return r;
}
static __device__ __forceinline__ float max3f(float a, float b, float c) {
  float r;
  asm("v_max3_f32 %0, %1, %2, %3" : "=v"(r) : "v"(a), "v"(b), "v"(c));
  return r;
}

// async global->LDS, 16B per lane; LDS dest is wave-uniform base + lane*16
#define GL16(g, l)                                                          \
  __builtin_amdgcn_global_load_lds(                                         \
      (const __attribute__((address_space(1))) unsigned int*)(g),           \
      (__attribute__((address_space(3))) unsigned int*)(l), 16, 0, 0)

// ---------------- batched transpose + cast + scale (3 weights, 1 launch) ----------------
__global__ __launch_bounds__(256) void k_transpose_cast_all(
    const float* __restrict__ Wq, unsigned short* __restrict__ WqT,
    const float* __restrict__ Wkv, unsigned short* __restrict__ WkvT,
    const float* __restrict__ Wo, unsigned short* __restrict__ WoT) {
  __shared__ float t[64][65];
  int bid = blockIdx.x;
  const float* W;
  unsigned short* WT;
  int K = 1024, N, n0, k0;
  float scale;
  if (bid < 256) {
    W = Wq; WT = WqT; N = 1024; scale = SC_FOLD;
    n0 = (bid & 15) * 64; k0 = (bid >> 4) * 64;
  } else if (bid < 768) {
    int b2 = bid - 256;
    W = Wkv; WT = WkvT; N = 2048; scale = 1.0f;
    n0 = (b2 & 31) * 64; k0 = (b2 >> 5) * 64;
  } else {
    int b2 = bid - 768;
    W = Wo; WT = WoT; N = 1024; scale = 1.0f;
    n0 = (b2 & 15) * 64; k0 = (b2 >> 4) * 64;
  }
  int tx = threadIdx.x & 63, ty = threadIdx.x >> 6;
#pragma unroll
  for (int i = 0; i < 64; i += 4)
    t[ty + i][tx] = W[(size_t)(k0 + ty + i) * N + n0 + tx];
  __syncthreads();
#pragma unroll
  for (int i = 0; i < 64; i += 4)
    WT[(size_t)(n0 + ty + i) * K + k0 + tx] = f2bf(t[tx][ty + i] * scale);
}

// ---------------- elementwise cast f32 -> bf16 ----------------
__global__ __launch_bounds__(256) void k_cast_bf16(
    const float* __restrict__ in, unsigned short* __restrict__ out, int n4) {
  for (int i = blockIdx.x * 256 + threadIdx.x; i < n4; i += gridDim.x * 256) {
    f32x4 v = *(const f32x4*)(in + (size_t)i * 4);
    unsigned long long u = (unsigned long long)pk2(v[0], v[1]) |
                           ((unsigned long long)pk2(v[2], v[3]) << 32);
    *(unsigned long long*)(out + (size_t)i * 4) = u;
  }
}

// ---------------- GEMM, 8-phase 256-row tile (T1+T2+T3+T4+T5) — unchanged R9 ----------------
template <int MODE, int BN>
__global__ __launch_bounds__(512, 2) void k_gemm8(
    const unsigned short* __restrict__ A, const unsigned short* __restrict__ BT,
    const float* __restrict__ bias, float bscale, unsigned short* __restrict__ out_a,
    unsigned short* __restrict__ out_b, float* __restrict__ out_f, int Kd) {
  constexpr int NI = BN / 64;
  constexpr int NH = NI / 2;
  __shared__ __align__(16) unsigned short As[2 * 256 * 64];
  __shared__ __align__(16) unsigned short Bs[2 * BN * 64];
  const int tid = threadIdx.x, lane = tid & 63, w = tid >> 6;
  const int wm = w >> 2, wn = w & 3;

  int nwg = gridDim.x * gridDim.y;
  int bid = blockIdx.y * gridDim.x + blockIdx.x;
  int cpx = nwg >> 3;
  int sw = (bid & 7) * cpx + (bid >> 3);
  int bx = sw % gridDim.x, by = sw / gridDim.x;
  int m0 = by * 256, n0 = bx * BN;

  const int strow = tid >> 3;
  const int sx = ((tid & 7) << 4) ^ ((strow & 7) << 4);
  const char* gA = (const char*)(A + (size_t)(m0 + strow) * Kd) + sx;
  const char* gB = (const char*)(BT + (size_t)(n0 + strow) * Kd) + sx;
  char* lA = (char*)As;
  char* lB = (char*)Bs;

#define ST_A(bf, c, k0) \
  GL16(gA + ((size_t)(c) * 64 * Kd + (size_t)(k0)) * 2, lA + (bf) * 32768 + (c) * 8192 + tid * 16)
#define ST_B(bf, c, k0) \
  GL16(gB + ((size_t)(c) * 64 * Kd + (size_t)(k0)) * 2, lB + (bf) * (BN * 128) + (c) * 8192 + tid * 16)

  f32x4 acc[8][NI];
#pragma unroll
  for (int i = 0; i < 8; ++i)
#pragma unroll
    for (int j = 0; j < NI; ++j) acc[i][j] = (f32x4){0.f, 0.f, 0.f, 0.f};

  s16x8 afr[4][2], bfr[NI][2];
  const int arow = wm * 128 + (lane & 15);
  const int brow = wn * (NI * 16) + (lane & 15);
  const int fcol = (lane >> 4) * 16;

#define RD_A(bf, r) (*(const s16x8*)(lA + (bf) * 32768 + (r) * 128 + ((fcol + _kk * 64) ^ (((r) & 7) << 4))))
#define RD_B(bf, r) (*(const s16x8*)(lB + (bf) * (BN * 128) + (r) * 128 + ((fcol + _kk * 64) ^ (((r) & 7) << 4))))

  const int nT = Kd >> 6;

  ST_B(0, 0, 0); ST_B(0, 1, 0);
  if (BN == 256) { ST_B(0, 2, 0); ST_B(0, 3, 0); }
  ST_A(0, 0, 0); ST_A(0, 2, 0);
  ST_A(0, 1, 0); ST_A(0, 3, 0);
  asm volatile("s_waitcnt vmcnt(2)" ::: "memory");
  __builtin_amdgcn_s_barrier();

#pragma unroll 1
  for (int t = 0; t < nT; ++t) {
    const int cur = t & 1, nxt = cur ^ 1;
    const int k1 = (t + 1) << 6;
    const bool st = (t + 1 < nT);

#pragma unroll
    for (int mi = 0; mi < 4; ++mi)
#pragma unroll
      for (int _kk = 0; _kk < 2; ++_kk) afr[mi][_kk] = RD_A(cur, arow + mi * 16);
#pragma unroll
    for (int ni = 0; ni < NH; ++ni)
#pragma unroll
      for (int _kk = 0; _kk < 2; ++_kk) bfr[ni][_kk] = RD_B(cur, brow + ni * 16);
    if (st) { ST_B(nxt, 0, k1); ST_B(nxt, 1, k1); }
    __builtin_amdgcn_s_barrier();
    __builtin_amdgcn_s_setprio(1);
#pragma unroll
    for (int mi = 0; mi < 4; ++mi)
#pragma unroll
      for (int ni = 0; ni < NH; ++ni)
#pragma unroll
        for (int kk = 0; kk < 2; ++kk)
          acc[mi][ni] = __builtin_amdgcn_mfma_f32_16x16x32_bf16(afr[mi][kk], bfr[ni][kk], acc[mi][ni], 0, 0, 0);
    __builtin_amdgcn_s_setprio(0);
    __builtin_amdgcn_s_barrier();

#pragma unroll
    for (int ni = NH; ni < NI; ++ni)
#pragma unroll
      for (int _kk = 0; _kk < 2; ++_kk) bfr[ni][_kk] = RD_B(cur, brow + ni * 16);
    if (st) {
      if (BN == 256) { ST_B(nxt, 2, k1); ST_B(nxt, 3, k1); }
      else           { ST_A(nxt, 0, k1); ST_A(nxt, 2, k1); }
    }
    if (st) asm volatile("s_waitcnt vmcnt(4)" ::: "memory");
    else    asm volatile("s_waitcnt vmcnt(0)" ::: "memory");
    __builtin_amdgcn_s_barrier();
    __builtin_amdgcn_s_setprio(1);
#pragma unroll
    for (int mi = 0; mi < 4; ++mi)
#pragma unroll
      for (int ni = NH; ni < NI; ++ni)
#pragma unroll
        for (int kk = 0; kk < 2; ++kk)
          acc[mi][ni] = __builtin_amdgcn_mfma_f32_16x16x32_bf16(afr[mi][kk], bfr[ni][kk], acc[mi][ni], 0, 0, 0);
    __builtin_amdgcn_s_setprio(0);
    __builtin_amdgcn_s_barrier();

#pragma unroll
    for (int mi = 0; mi < 4; ++mi)
#pragma unroll
      for (int _kk = 0; _kk < 2; ++_kk) afr[mi][_kk] = RD_A(cur, arow + (mi + 4) * 16);
    if (st) {
      if (BN == 256) { ST_A(nxt, 0, k1); ST_A(nxt, 2, k1); }
      else           { ST_A(nxt, 1, k1); ST_A(nxt, 3, k1); }
    }
    __builtin_amdgcn_s_barrier();
    __builtin_amdgcn_s_setprio(1);
#pragma unroll
    for (int mi = 0; mi < 4; ++mi)
#pragma unroll
      for (int ni = 0; ni < NH; ++ni)
#pragma unroll
        for (int kk = 0; kk < 2; ++kk)
          acc[mi + 4][ni] = __builtin_amdgcn_mfma_f32_16x16x32_bf16(afr[mi][kk], bfr[ni][kk], acc[mi + 4][ni], 0, 0, 0);
    __builtin_amdgcn_s_setprio(0);
    __builtin_amdgcn_s_barrier();

    if (st && BN == 256) { ST_A(nxt, 1, k1); ST_A(nxt, 3, k1); }
    asm volatile("s_waitcnt vmcnt(2)" ::: "memory");
    __builtin_amdgcn_s_barrier();
    __builtin_amdgcn_s_setprio(1);
#pragma unroll
    for (int mi = 0; mi < 4; ++mi)
#pragma unroll
      for (int ni = NH; ni < NI; ++ni)
#pragma unroll
        for (int kk = 0; kk < 2; ++kk)
          acc[mi + 4][ni] = __builtin_amdgcn_mfma_f32_16x16x32_bf16(afr[mi][kk], bfr[ni][kk], acc[mi + 4][ni], 0, 0, 0);
    __builtin_amdgcn_s_setprio(0);
    __builtin_amdgcn_s_barrier();
  }

#pragma unroll
  for (int mi = 0; mi < 8; ++mi) {
#pragma unroll
    for (int ni = 0; ni < NI; ++ni) {
      int col = n0 + wn * (NI * 16) + ni * 16 + (lane & 15);
      int rbase = m0 + wm * 128 + mi * 16 + (lane >> 4) * 4;
      float bv = bias[col] * bscale;
      if (MODE == 1 && col >= H_ * DH_) {
        int c2 = col - H_ * DH_;
        int h = c2 >> 6, d = c2 & 63;
        int b = rbase >> 11, tt = rbase & 2047;
        union { unsigned short h4[4]; unsigned long long u; } p;
#pragma unroll
        for (int r = 0; r < 4; ++r) p.h4[r] = f2bf(acc[mi][ni][r] + bv);
        *(unsigned long long*)(out_b + ((((size_t)b * H_ + h) * DH_ + d) * TKV_ + tt)) = p.u;
      } else {
#pragma unroll
        for (int r = 0; r < 4; ++r) {
          float v = acc[mi][ni][r] + bv;
          int m = rbase + r;
          if (MODE == 0) {
            int b = m >> 11, tt = m & 2047;
            int h = col >> 6, d = col & 63;
            out_a[(((size_t)b * H_ + h) * TQ_ + tt) * DH_ + d] = f2bf(v);
          } else if (MODE == 1) {
            int b = m >> 11, tt = m & 2047;
            int h = col >> 6, d = col & 63;
            out_a[(((size_t)b * H_ + h) * TKV_ + tt) * DH_ + d] = f2bf(v);
          } else {
            out_f[(size_t)m * DM_ + col] = v;
          }
        }
      }
    }
  }
#undef ST_A
#undef ST_B
#undef RD_A
#undef RD_B
}

// ---------------- flash attention: KVBLK=128, dbuf LDS, permlane32_swap pack ----------------
// grid (8, 64) x 256 threads = 4 waves x 32 q-rows; paired q-tiles (bx, 15-bx).
// Double-buffered K/V, one barrier per tile. (R13-verified best: 86.4 us)
__global__ __launch_bounds__(256, 2) void k_attn(
    const unsigned short* __restrict__ Qb, const unsigned short* __restrict__ Kb,
    const unsigned short* __restrict__ Vtb, const unsigned char* __restrict__ mask,
    const int* __restrict__ cflag, unsigned short* __restrict__ Ob) {
  __shared__ __align__(16) unsigned short Kt[2][128 * 64];  // [buf][kv][d], XOR-swizzled
  __shared__ __align__(16) unsigned short Vt[2][64 * 128];  // [buf][d][kv], XOR-swizzled
  __shared__ float bias_lds[2][128];
  __shared__ float red[4][32];
  __shared__ int s_any;

  // XCD head-locality swizzle: 8 q-blocks of a head on one XCD
  int bid = blockIdx.y * gridDim.x + blockIdx.x;
  int r8 = bid & 7, q8 = bid >> 3;
  int bh = r8 * 8 + (q8 >> 3);
  int bx = q8 & 7;

  int b = bh >> 4, h = bh & 15;
  int tid = threadIdx.x, lane = tid & 63, w = tid >> 6;
  int hi = lane >> 5, l31 = lane & 31, l7 = lane & 7;
  const unsigned short* Qp = Qb + (size_t)bh * TQ_ * DH_;
  const char* Kp = (const char*)(Kb + (size_t)bh * TKV_ * DH_);
  const char* Vp = (const char*)(Vtb + (size_t)bh * DH_ * TKV_);
  const unsigned char* mp = mask + (size_t)b * TKV_;
  int causal = cflag[0];

  // staging: K 128x128B rows (4x16B/thread), V 64x256B rows (4x16B/thread)
  int st_r4 = tid >> 2;            // 0..63
  int st_c4 = (tid & 3) * 16;      // 0,16,32,48
  s16x8 pKr[4], pVr[4];

#define LOAD_KV(kv0)                                                          \
  {                                                                           \
    _Pragma("unroll")                                                         \
    for (int p = 0; p < 4; ++p) {                                             \
      int krow = (p >> 1) * 64 + st_r4;                                       \
      int kx = st_c4 + (p & 1) * 64;                                          \
      pKr[p] = *(const s16x8*)(Kp + ((size_t)((kv0) + krow) * 128 + kx));     \
      int vx = st_c4 + p * 64;                                                \
      pVr[p] = *(const s16x8*)(Vp + (((size_t)st_r4 * TKV_ + (kv0)) * 2 + vx)); \
    }                                                                         \
  }
#define WRITE_KV(bufi)                                                        \
  {                                                                           \
    char* kb_ = (char*)&Kt[bufi][0];                                          \
    char* vb_ = (char*)&Vt[bufi][0];                                          \
    _Pragma("unroll")                                                         \
    for (int p = 0; p < 4; ++p) {                                             \
      int krow = (p >> 1) * 64 + st_r4;                                       \
      int kx = st_c4 + (p & 1) * 64;                                          \
      *(s16x8*)(kb_ + krow * 128 + (kx ^ ((st_r4 & 7) << 4))) = pKr[p];       \
      int vx = st_c4 + p * 64;                                                \
      *(s16x8*)(vb_ + st_r4 * 256 + (vx ^ ((st_r4 & 7) << 4))) = pVr[p];      \
    }                                                                         \
  }

  if (tid == 0) s_any = 0;
  __syncthreads();
  {
    int any = 0;
    for (int i = tid; i < TKV_; i += 256) any |= mp[i];
    if (any) s_any = 1;
  }
  __syncthreads();
  const int has_mask = s_any;

#pragma unroll 1
  for (int pass = 0; pass < 2; ++pass) {
    int qb = (pass ? (15 - bx) : bx) * 128;
    int qw = qb + w * 32;
    int qrow = qw + l31;

    s16x8 bQ[4];
#pragma unroll
    for (int kk = 0; kk < 4; ++kk)
      bQ[kk] = *(const s16x8*)(Qp + (size_t)qrow * DH_ + kk * 16 + hi * 8);

    f32x16 accO[2];
#pragma unroll
    for (int i = 0; i < 16; ++i) { accO[0][i] = 0.f; accO[1][i] = 0.f; }
    float m_run = -INFINITY, l_run = 0.f;

    int nT = (causal ? (qb + 128) : TKV_) >> 7;

    // prologue: stage tile 0 into buf 0
    LOAD_KV(0);
    WRITE_KV(0);
    if (has_mask && tid < 128) bias_lds[0][tid] = mp[tid] ? -1e30f : 0.0f;
    __syncthreads();

#pragma unroll 1
    for (int it = 0; it < nT; ++it) {
      int kv0 = it << 7;
      int cur = it & 1, nxt = cur ^ 1;
      if (it + 1 < nT) LOAD_KV(kv0 + 128);  // issue next-tile loads (T14)

      char* kbase = (char*)&Kt[cur][0];
      char* vbase = (char*)&Vt[cur][0];

      // wave-uniform active sub-tile count (32-kv granularity)
      int nact = 4;
      if (causal) {
        int rem = qw + 31 - kv0;
        nact = rem < 0 ? 0 : ((rem >> 5) + 1);
        if (nact > 4) nact = 4;
      }

      if (nact > 0) {
        f32x16 sT[4];
        __builtin_amdgcn_s_setprio(1);
#pragma unroll
        for (int s = 0; s < 4; ++s) {
          if (s < nact) {
#pragma unroll
            for (int i = 0; i < 16; ++i) sT[s][i] = 0.f;
#pragma unroll
            for (int kk = 0; kk < 4; ++kk) {
              s16x8 aK = *(const s16x8*)(kbase + (s * 32 + l31) * 128 +
                                         ((kk * 32 + hi * 16) ^ (l7 << 4)));
              sT[s] = __builtin_amdgcn_mfma_f32_32x32x16_bf16(aK, bQ[kk], sT[s], 0, 0, 0);
            }
          }
        }
        __builtin_amdgcn_s_setprio(0);

        // masks + row-max over active sub-tiles (4 parallel accumulators)
        float a0 = -INFINITY, a1 = -INFINITY, a2 = -INFINITY, a3 = -INFINITY;
#pragma unroll
        for (int s = 0; s < 4; ++s) {
          if (s < nact) {
            int diag_s = causal && (kv0 + s * 32 + 31 > qw);  // wave-uniform
            if (diag_s || has_mask) {
#pragma unroll
              for (int r = 0; r < 16; ++r) {
                int kvloc = s * 32 + (r & 3) + 8 * (r >> 2) + 4 * hi;
                float sv = sT[s][r];
                if (has_mask) sv += bias_lds[cur][kvloc];
                if (diag_s && (kv0 + kvloc) > qrow) sv = -1e30f;
                sT[s][r] = sv;
              }
            }
#pragma unroll
            for (int r = 0; r < 16; r += 4) {
              a0 = fmaxf(a0, sT[s][r + 0]); a1 = fmaxf(a1, sT[s][r + 1]);
              a2 = fmaxf(a2, sT[s][r + 2]); a3 = fmaxf(a3, sT[s][r + 3]);
            }
          }
        }
        float mx = max3f(max3f(a0, a1, a2), a3, -3.0e30f);
        mx = fmaxf(mx, __shfl_xor(mx, 32));

        // T13 defer-rescale
        if (!__all(mx - m_run <= 8.0f)) {
          float mnew = fmaxf(m_run, mx);
          float sc_o = exp2f(m_run - mnew);
          m_run = mnew;
          l_run *= sc_o;
          red[w][l31] = sc_o;
#pragma unroll
          for (int r = 0; r < 16; ++r) {
            float f = red[w][(r & 3) + 8 * (r >> 2) + 4 * hi];
            accO[0][r] *= f;
            accO[1][r] *= f;
          }
        }

        // exp + 4-way parallel partial sums (active sub-tiles only)
        float s0acc = 0.f, s1acc = 0.f, s2acc = 0.f, s3acc = 0.f;
#pragma unroll
        for (int s = 0; s < 4; ++s) {
          if (s < nact) {
#pragma unroll
            for (int r = 0; r < 16; r += 4) {
              float p0 = exp2f(sT[s][r + 0] - m_run);
              float p1 = exp2f(sT[s][r + 1] - m_run);
              float p2 = exp2f(sT[s][r + 2] - m_run);
              float p3 = exp2f(sT[s][r + 3] - m_run);
              sT[s][r + 0] = p0; sT[s][r + 1] = p1;
              sT[s][r + 2] = p2; sT[s][r + 3] = p3;
              s0acc += p0; s1acc += p1; s2acc += p2; s3acc += p3;
            }
          }
        }
        float ls = (s0acc + s1acc) + (s2acc + s3acc);
        ls += __shfl_xor(ls, 32);
        l_run += ls;

        // P -> A-frag via cvt_pk + permlane32_swap (T12) + PV
#pragma unroll
        for (int c = 0; c < 8; ++c) {
          if ((c >> 1) < nact) {
            int s = c >> 1, kk = c & 1;
            unsigned int x0 = pk2(sT[s][8 * kk + 0], sT[s][8 * kk + 1]);
            unsigned int y0 = pk2(sT[s][8 * kk + 2], sT[s][8 * kk + 3]);
            unsigned int x1 = pk2(sT[s][8 * kk + 4], sT[s][8 * kk + 5]);
            unsigned int y1 = pk2(sT[s][8 * kk + 6], sT[s][8 * kk + 7]);
            asm("v_permlane32_swap_b32 %0, %1" : "+v"(x0), "+v"(x1));
            asm("v_permlane32_swap_b32 %0, %1" : "+v"(y0), "+v"(y1));
            union { unsigned int u[4]; s16x8 v; } pf;
            pf.u[0] = x0;
            pf.u[1] = y0;
            pf.u[2] = x1;
            pf.u[3] = y1;
            __builtin_amdgcn_s_setprio(1);
#pragma unroll
            for (int dt = 0; dt < 2; ++dt) {
              s16x8 vf = *(const s16x8*)(vbase + (dt * 32 + l31) * 256 +
                                         ((c * 32 + hi * 16) ^ (l7 << 4)));
              accO[dt] = __builtin_amdgcn_mfma_f32_32x32x16_bf16(pf.v, vf, accO[dt], 0, 0, 0);
            }
            __builtin_amdgcn_s_setprio(0);
          }
        }
      }

      // write next tile into the other buffer, then ONE barrier (both hazards)
      if (it + 1 < nT) {
        WRITE_KV(nxt);
        if (has_mask && tid < 128) bias_lds[nxt][tid] = mp[kv0 + 128 + tid] ? -1e30f : 0.0f;
      }
      __syncthreads();
    }

    // epilogue
    red[w][l31] = 1.0f / l_run;
#pragma unroll
    for (int r = 0; r < 16; ++r) {
      int R = (r & 3) + 8 * (r >> 2) + 4 * hi;
      float f = red[w][R];
      int qg = qw + R;
      size_t base = ((size_t)b * TQ_ + qg) * DM_ + h * DH_ + l31;
      Ob[base] = f2bf(accO[0][r] * f);
      Ob[base + 32] = f2bf(accO[1][r] * f);
    }
  }
#undef LOAD_KV
#undef WRITE_KV
}

extern "C" void kernel_launch(void* const* d_in, const int* in_sizes, int n_in,
                              void* d_out, int out_size, void* d_ws, size_t ws_size,
                              hipStream_t stream) {
  const float* xq  = (const float*)d_in[0];
  const float* xkv = (const float*)d_in[1];
  const unsigned char* mask = (const unsigned char*)d_in[2];
  const float* Wq  = (const float*)d_in[3];
  const float* bq  = (const float*)d_in[4];
  const float* Wkv = (const float*)d_in[5];
  const float* bkv = (const float*)d_in[6];
  const float* Wo  = (const float*)d_in[7];
  const float* bo  = (const float*)d_in[8];
  const int* cflag = (const int*)d_in[9];
  float* out = (float*)d_out;

  char* ws = (char*)d_ws;
  unsigned short* WqT  = (unsigned short*)(ws);                       // 2 MiB
  unsigned short* WkvT = (unsigned short*)(ws + ((size_t)2 << 20));   // 4 MiB
  unsigned short* WoT  = (unsigned short*)(ws + ((size_t)6 << 20));   // 2 MiB
  unsigned short* Qb   = (unsigned short*)(ws + ((size_t)8 << 20));   // [B,H,TQ,64]
  unsigned short* Kb   = (unsigned short*)(ws + ((size_t)24 << 20));  // [B,H,TKV,64]
  unsigned short* Vb   = (unsigned short*)(ws + ((size_t)40 << 20));  // [B,H,64,TKV]
  unsigned short* Xr   = (unsigned short*)(ws + ((size_t)56 << 20));  // Aq -> Akv -> Ob
  unsigned short* Ob   = Xr;

  k_transpose_cast_all<<<1024, 256, 0, stream>>>(Wq, WqT, Wkv, WkvT, Wo, WoT);

  k_cast_bf16<<<2048, 256, 0, stream>>>(xq, Xr, B_ * TQ_ * DM_ / 4);
  k_gemm8<0, 128><<<dim3(8, 32), 512, 0, stream>>>(Xr, WqT, bq, SC_FOLD, Qb, nullptr, nullptr, 1024);

  k_cast_bf16<<<2048, 256, 0, stream>>>(xkv, Xr, B_ * TKV_ * DM_ / 4);
  k_gemm8<1, 256><<<dim3(8, 32), 512, 0, stream>>>(Xr, WkvT, bkv, 1.0f, Kb, Vb, nullptr, 1024);

  k_attn<<<dim3(8, B_ * H_), 256, 0, stream>>>(Qb, Kb, Vb, mask, cflag, Ob);

  k_gemm8<2, 128><<<dim3(8, 32), 512, 0, stream>>>(Ob, WoT, bo, 1.0f, nullptr, nullptr, out, 1024);
}

// Round 17
// 188.759 us; speedup vs baseline: 1.8814x; 1.0173x over previous
//
#include <hip/hip_runtime.h>
#include <hip/hip_bf16.h>

#define B_   4
#define TQ_  2048
#define TKV_ 2048
#define DM_  1024
#define H_   16
#define DH_  64

// 1/sqrt(DK) * log2(e), folded into Wq/bq so attention exp2 needs no scaling
#define SC_FOLD 0.18033688011112042f

using f32x4  = __attribute__((ext_vector_type(4))) float;
using f32x16 = __attribute__((ext_vector_type(16))) float;
using s16x8  = __attribute__((ext_vector_type(8))) short;

static __device__ __forceinline__ unsigned short f2bf(float f) {
  union { float f; unsigned int u; } v; v.f = f;
  unsigned int r = v.u + 0x7FFFu + ((v.u >> 16) & 1u);
  return (unsigned short)(r >> 16);
}
// packed f32 pair -> 2xbf16 (RNE) in one instruction
static __device__ __forceinline__ unsigned int pk2(float a, float b) {
  unsigned int r;
  asm("v_cvt_pk_bf16_f32 %0, %1, %2" : "=v"(r) : "v"(a), "v"(b));
  return r;
}
static __device__ __forceinline__ float max3f(float a, float b, float c) {
  float r;
  asm("v_max3_f32 %0, %1, %2, %3" : "=v"(r) : "v"(a), "v"(b), "v"(c));
  return r;
}

// async global->LDS, 16B per lane; LDS dest is wave-uniform base + lane*16
#define GL16(g, l)                                                          \
  __builtin_amdgcn_global_load_lds(                                         \
      (const __attribute__((address_space(1))) unsigned int*)(g),           \
      (__attribute__((address_space(3))) unsigned int*)(l), 16, 0, 0)

// ---------------- fused prep: 3 weight transposes + xq cast (1 launch) ----------------
// blocks [0,256)=Wq^T, [256,768)=Wkv^T, [768,1024)=Wo^T, [1024,3072)=cast xq
__global__ __launch_bounds__(256) void k_prep(
    const float* __restrict__ Wq, unsigned short* __restrict__ WqT,
    const float* __restrict__ Wkv, unsigned short* __restrict__ WkvT,
    const float* __restrict__ Wo, unsigned short* __restrict__ WoT,
    const float* __restrict__ xq, unsigned short* __restrict__ Aq, int n4) {
  int bid = blockIdx.x;
  if (bid >= 1024) {
    int cb = bid - 1024;  // 2048 cast blocks, grid-stride
    for (int i = cb * 256 + threadIdx.x; i < n4; i += 2048 * 256) {
      f32x4 v = *(const f32x4*)(xq + (size_t)i * 4);
      unsigned long long u = (unsigned long long)pk2(v[0], v[1]) |
                             ((unsigned long long)pk2(v[2], v[3]) << 32);
      *(unsigned long long*)(Aq + (size_t)i * 4) = u;
    }
    return;
  }
  __shared__ float t[64][65];
  const float* W;
  unsigned short* WT;
  int K = 1024, N, n0, k0;
  float scale;
  if (bid < 256) {
    W = Wq; WT = WqT; N = 1024; scale = SC_FOLD;
    n0 = (bid & 15) * 64; k0 = (bid >> 4) * 64;
  } else if (bid < 768) {
    int b2 = bid - 256;
    W = Wkv; WT = WkvT; N = 2048; scale = 1.0f;
    n0 = (b2 & 31) * 64; k0 = (b2 >> 5) * 64;
  } else {
    int b2 = bid - 768;
    W = Wo; WT = WoT; N = 1024; scale = 1.0f;
    n0 = (b2 & 15) * 64; k0 = (b2 >> 4) * 64;
  }
  int tx = threadIdx.x & 63, ty = threadIdx.x >> 6;
#pragma unroll
  for (int i = 0; i < 64; i += 4)
    t[ty + i][tx] = W[(size_t)(k0 + ty + i) * N + n0 + tx];
  __syncthreads();
#pragma unroll
  for (int i = 0; i < 64; i += 4)
    WT[(size_t)(n0 + ty + i) * K + k0 + tx] = f2bf(t[tx][ty + i] * scale);
}

// ---------------- elementwise cast f32 -> bf16 ----------------
__global__ __launch_bounds__(256) void k_cast_bf16(
    const float* __restrict__ in, unsigned short* __restrict__ out, int n4) {
  for (int i = blockIdx.x * 256 + threadIdx.x; i < n4; i += gridDim.x * 256) {
    f32x4 v = *(const f32x4*)(in + (size_t)i * 4);
    unsigned long long u = (unsigned long long)pk2(v[0], v[1]) |
                           ((unsigned long long)pk2(v[2], v[3]) << 32);
    *(unsigned long long*)(out + (size_t)i * 4) = u;
  }
}

// ---------------- GEMM, 8-phase 256-row tile (T1+T2+T3+T4+T5) — unchanged R9 ----------------
template <int MODE, int BN>
__global__ __launch_bounds__(512, 2) void k_gemm8(
    const unsigned short* __restrict__ A, const unsigned short* __restrict__ BT,
    const float* __restrict__ bias, float bscale, unsigned short* __restrict__ out_a,
    unsigned short* __restrict__ out_b, float* __restrict__ out_f, int Kd) {
  constexpr int NI = BN / 64;
  constexpr int NH = NI / 2;
  __shared__ __align__(16) unsigned short As[2 * 256 * 64];
  __shared__ __align__(16) unsigned short Bs[2 * BN * 64];
  const int tid = threadIdx.x, lane = tid & 63, w = tid >> 6;
  const int wm = w >> 2, wn = w & 3;

  int nwg = gridDim.x * gridDim.y;
  int bid = blockIdx.y * gridDim.x + blockIdx.x;
  int cpx = nwg >> 3;
  int sw = (bid & 7) * cpx + (bid >> 3);
  int bx = sw % gridDim.x, by = sw / gridDim.x;
  int m0 = by * 256, n0 = bx * BN;

  const int strow = tid >> 3;
  const int sx = ((tid & 7) << 4) ^ ((strow & 7) << 4);
  const char* gA = (const char*)(A + (size_t)(m0 + strow) * Kd) + sx;
  const char* gB = (const char*)(BT + (size_t)(n0 + strow) * Kd) + sx;
  char* lA = (char*)As;
  char* lB = (char*)Bs;

#define ST_A(bf, c, k0) \
  GL16(gA + ((size_t)(c) * 64 * Kd + (size_t)(k0)) * 2, lA + (bf) * 32768 + (c) * 8192 + tid * 16)
#define ST_B(bf, c, k0) \
  GL16(gB + ((size_t)(c) * 64 * Kd + (size_t)(k0)) * 2, lB + (bf) * (BN * 128) + (c) * 8192 + tid * 16)

  f32x4 acc[8][NI];
#pragma unroll
  for (int i = 0; i < 8; ++i)
#pragma unroll
    for (int j = 0; j < NI; ++j) acc[i][j] = (f32x4){0.f, 0.f, 0.f, 0.f};

  s16x8 afr[4][2], bfr[NI][2];
  const int arow = wm * 128 + (lane & 15);
  const int brow = wn * (NI * 16) + (lane & 15);
  const int fcol = (lane >> 4) * 16;

#define RD_A(bf, r) (*(const s16x8*)(lA + (bf) * 32768 + (r) * 128 + ((fcol + _kk * 64) ^ (((r) & 7) << 4))))
#define RD_B(bf, r) (*(const s16x8*)(lB + (bf) * (BN * 128) + (r) * 128 + ((fcol + _kk * 64) ^ (((r) & 7) << 4))))

  const int nT = Kd >> 6;

  ST_B(0, 0, 0); ST_B(0, 1, 0);
  if (BN == 256) { ST_B(0, 2, 0); ST_B(0, 3, 0); }
  ST_A(0, 0, 0); ST_A(0, 2, 0);
  ST_A(0, 1, 0); ST_A(0, 3, 0);
  asm volatile("s_waitcnt vmcnt(2)" ::: "memory");
  __builtin_amdgcn_s_barrier();

#pragma unroll 1
  for (int t = 0; t < nT; ++t) {
    const int cur = t & 1, nxt = cur ^ 1;
    const int k1 = (t + 1) << 6;
    const bool st = (t + 1 < nT);

#pragma unroll
    for (int mi = 0; mi < 4; ++mi)
#pragma unroll
      for (int _kk = 0; _kk < 2; ++_kk) afr[mi][_kk] = RD_A(cur, arow + mi * 16);
#pragma unroll
    for (int ni = 0; ni < NH; ++ni)
#pragma unroll
      for (int _kk = 0; _kk < 2; ++_kk) bfr[ni][_kk] = RD_B(cur, brow + ni * 16);
    if (st) { ST_B(nxt, 0, k1); ST_B(nxt, 1, k1); }
    __builtin_amdgcn_s_barrier();
    __builtin_amdgcn_s_setprio(1);
#pragma unroll
    for (int mi = 0; mi < 4; ++mi)
#pragma unroll
      for (int ni = 0; ni < NH; ++ni)
#pragma unroll
        for (int kk = 0; kk < 2; ++kk)
          acc[mi][ni] = __builtin_amdgcn_mfma_f32_16x16x32_bf16(afr[mi][kk], bfr[ni][kk], acc[mi][ni], 0, 0, 0);
    __builtin_amdgcn_s_setprio(0);
    __builtin_amdgcn_s_barrier();

#pragma unroll
    for (int ni = NH; ni < NI; ++ni)
#pragma unroll
      for (int _kk = 0; _kk < 2; ++_kk) bfr[ni][_kk] = RD_B(cur, brow + ni * 16);
    if (st) {
      if (BN == 256) { ST_B(nxt, 2, k1); ST_B(nxt, 3, k1); }
      else           { ST_A(nxt, 0, k1); ST_A(nxt, 2, k1); }
    }
    if (st) asm volatile("s_waitcnt vmcnt(4)" ::: "memory");
    else    asm volatile("s_waitcnt vmcnt(0)" ::: "memory");
    __builtin_amdgcn_s_barrier();
    __builtin_amdgcn_s_setprio(1);
#pragma unroll
    for (int mi = 0; mi < 4; ++mi)
#pragma unroll
      for (int ni = NH; ni < NI; ++ni)
#pragma unroll
        for (int kk = 0; kk < 2; ++kk)
          acc[mi][ni] = __builtin_amdgcn_mfma_f32_16x16x32_bf16(afr[mi][kk], bfr[ni][kk], acc[mi][ni], 0, 0, 0);
    __builtin_amdgcn_s_setprio(0);
    __builtin_amdgcn_s_barrier();

#pragma unroll
    for (int mi = 0; mi < 4; ++mi)
#pragma unroll
      for (int _kk = 0; _kk < 2; ++_kk) afr[mi][_kk] = RD_A(cur, arow + (mi + 4) * 16);
    if (st) {
      if (BN == 256) { ST_A(nxt, 0, k1); ST_A(nxt, 2, k1); }
      else           { ST_A(nxt, 1, k1); ST_A(nxt, 3, k1); }
    }
    __builtin_amdgcn_s_barrier();
    __builtin_amdgcn_s_setprio(1);
#pragma unroll
    for (int mi = 0; mi < 4; ++mi)
#pragma unroll
      for (int ni = 0; ni < NH; ++ni)
#pragma unroll
        for (int kk = 0; kk < 2; ++kk)
          acc[mi + 4][ni] = __builtin_amdgcn_mfma_f32_16x16x32_bf16(afr[mi][kk], bfr[ni][kk], acc[mi + 4][ni], 0, 0, 0);
    __builtin_amdgcn_s_setprio(0);
    __builtin_amdgcn_s_barrier();

    if (st && BN == 256) { ST_A(nxt, 1, k1); ST_A(nxt, 3, k1); }
    asm volatile("s_waitcnt vmcnt(2)" ::: "memory");
    __builtin_amdgcn_s_barrier();
    __builtin_amdgcn_s_setprio(1);
#pragma unroll
    for (int mi = 0; mi < 4; ++mi)
#pragma unroll
      for (int ni = NH; ni < NI; ++ni)
#pragma unroll
        for (int kk = 0; kk < 2; ++kk)
          acc[mi + 4][ni] = __builtin_amdgcn_mfma_f32_16x16x32_bf16(afr[mi][kk], bfr[ni][kk], acc[mi + 4][ni], 0, 0, 0);
    __builtin_amdgcn_s_setprio(0);
    __builtin_amdgcn_s_barrier();
  }

#pragma unroll
  for (int mi = 0; mi < 8; ++mi) {
#pragma unroll
    for (int ni = 0; ni < NI; ++ni) {
      int col = n0 + wn * (NI * 16) + ni * 16 + (lane & 15);
      int rbase = m0 + wm * 128 + mi * 16 + (lane >> 4) * 4;
      float bv = bias[col] * bscale;
      if (MODE == 1 && col >= H_ * DH_) {
        int c2 = col - H_ * DH_;
        int h = c2 >> 6, d = c2 & 63;
        int b = rbase >> 11, tt = rbase & 2047;
        union { unsigned short h4[4]; unsigned long long u; } p;
#pragma unroll
        for (int r = 0; r < 4; ++r) p.h4[r] = f2bf(acc[mi][ni][r] + bv);
        *(unsigned long long*)(out_b + ((((size_t)b * H_ + h) * DH_ + d) * TKV_ + tt)) = p.u;
      } else {
#pragma unroll
        for (int r = 0; r < 4; ++r) {
          float v = acc[mi][ni][r] + bv;
          int m = rbase + r;
          if (MODE == 0) {
            int b = m >> 11, tt = m & 2047;
            int h = col >> 6, d = col & 63;
            out_a[(((size_t)b * H_ + h) * TQ_ + tt) * DH_ + d] = f2bf(v);
          } else if (MODE == 1) {
            int b = m >> 11, tt = m & 2047;
            int h = col >> 6, d = col & 63;
            out_a[(((size_t)b * H_ + h) * TKV_ + tt) * DH_ + d] = f2bf(v);
          } else {
            out_f[(size_t)m * DM_ + col] = v;
          }
        }
      }
    }
  }
#undef ST_A
#undef ST_B
#undef RD_A
#undef RD_B
}

// ---------------- flash attention: KVBLK=128, dbuf LDS, permlane32_swap pack ----------------
// grid (8, 64) x 256 threads = 4 waves x 32 q-rows; paired q-tiles (bx, 15-bx).
// Double-buffered K/V, one barrier per tile. (R13-verified best: ~86 us)
__global__ __launch_bounds__(256, 2) void k_attn(
    const unsigned short* __restrict__ Qb, const unsigned short* __restrict__ Kb,
    const unsigned short* __restrict__ Vtb, const unsigned char* __restrict__ mask,
    const int* __restrict__ cflag, unsigned short* __restrict__ Ob) {
  __shared__ __align__(16) unsigned short Kt[2][128 * 64];  // [buf][kv][d], XOR-swizzled
  __shared__ __align__(16) unsigned short Vt[2][64 * 128];  // [buf][d][kv], XOR-swizzled
  __shared__ float bias_lds[2][128];
  __shared__ float red[4][32];
  __shared__ int s_any;

  // XCD head-locality swizzle: 8 q-blocks of a head on one XCD
  int bid = blockIdx.y * gridDim.x + blockIdx.x;
  int r8 = bid & 7, q8 = bid >> 3;
  int bh = r8 * 8 + (q8 >> 3);
  int bx = q8 & 7;

  int b = bh >> 4, h = bh & 15;
  int tid = threadIdx.x, lane = tid & 63, w = tid >> 6;
  int hi = lane >> 5, l31 = lane & 31, l7 = lane & 7;
  const unsigned short* Qp = Qb + (size_t)bh * TQ_ * DH_;
  const char* Kp = (const char*)(Kb + (size_t)bh * TKV_ * DH_);
  const char* Vp = (const char*)(Vtb + (size_t)bh * DH_ * TKV_);
  const unsigned char* mp = mask + (size_t)b * TKV_;
  int causal = cflag[0];

  // staging: K 128x128B rows (4x16B/thread), V 64x256B rows (4x16B/thread)
  int st_r4 = tid >> 2;            // 0..63
  int st_c4 = (tid & 3) * 16;      // 0,16,32,48
  s16x8 pKr[4], pVr[4];

#define LOAD_KV(kv0)                                                          \
  {                                                                           \
    _Pragma("unroll")                                                         \
    for (int p = 0; p < 4; ++p) {                                             \
      int krow = (p >> 1) * 64 + st_r4;                                       \
      int kx = st_c4 + (p & 1) * 64;                                          \
      pKr[p] = *(const s16x8*)(Kp + ((size_t)((kv0) + krow) * 128 + kx));     \
      int vx = st_c4 + p * 64;                                                \
      pVr[p] = *(const s16x8*)(Vp + (((size_t)st_r4 * TKV_ + (kv0)) * 2 + vx)); \
    }                                                                         \
  }
#define WRITE_KV(bufi)                                                        \
  {                                                                           \
    char* kb_ = (char*)&Kt[bufi][0];                                          \
    char* vb_ = (char*)&Vt[bufi][0];                                          \
    _Pragma("unroll")                                                         \
    for (int p = 0; p < 4; ++p) {                                             \
      int krow = (p >> 1) * 64 + st_r4;                                       \
      int kx = st_c4 + (p & 1) * 64;                                          \
      *(s16x8*)(kb_ + krow * 128 + (kx ^ ((st_r4 & 7) << 4))) = pKr[p];       \
      int vx = st_c4 + p * 64;                                                \
      *(s16x8*)(vb_ + st_r4 * 256 + (vx ^ ((st_r4 & 7) << 4))) = pVr[p];      \
    }                                                                         \
  }

  if (tid == 0) s_any = 0;
  __syncthreads();
  {
    int any = 0;
    for (int i = tid; i < TKV_; i += 256) any |= mp[i];
    if (any) s_any = 1;
  }
  __syncthreads();
  const int has_mask = s_any;

#pragma unroll 1
  for (int pass = 0; pass < 2; ++pass) {
    int qb = (pass ? (15 - bx) : bx) * 128;
    int qw = qb + w * 32;
    int qrow = qw + l31;

    s16x8 bQ[4];
#pragma unroll
    for (int kk = 0; kk < 4; ++kk)
      bQ[kk] = *(const s16x8*)(Qp + (size_t)qrow * DH_ + kk * 16 + hi * 8);

    f32x16 accO[2];
#pragma unroll
    for (int i = 0; i < 16; ++i) { accO[0][i] = 0.f; accO[1][i] = 0.f; }
    float m_run = -INFINITY, l_run = 0.f;

    int nT = (causal ? (qb + 128) : TKV_) >> 7;

    // prologue: stage tile 0 into buf 0
    LOAD_KV(0);
    WRITE_KV(0);
    if (has_mask && tid < 128) bias_lds[0][tid] = mp[tid] ? -1e30f : 0.0f;
    __syncthreads();

#pragma unroll 1
    for (int it = 0; it < nT; ++it) {
      int kv0 = it << 7;
      int cur = it & 1, nxt = cur ^ 1;
      if (it + 1 < nT) LOAD_KV(kv0 + 128);  // issue next-tile loads (T14)

      char* kbase = (char*)&Kt[cur][0];
      char* vbase = (char*)&Vt[cur][0];

      // wave-uniform active sub-tile count (32-kv granularity)
      int nact = 4;
      if (causal) {
        int rem = qw + 31 - kv0;
        nact = rem < 0 ? 0 : ((rem >> 5) + 1);
        if (nact > 4) nact = 4;
      }

      if (nact > 0) {
        f32x16 sT[4];
        __builtin_amdgcn_s_setprio(1);
#pragma unroll
        for (int s = 0; s < 4; ++s) {
          if (s < nact) {
#pragma unroll
            for (int i = 0; i < 16; ++i) sT[s][i] = 0.f;
#pragma unroll
            for (int kk = 0; kk < 4; ++kk) {
              s16x8 aK = *(const s16x8*)(kbase + (s * 32 + l31) * 128 +
                                         ((kk * 32 + hi * 16) ^ (l7 << 4)));
              sT[s] = __builtin_amdgcn_mfma_f32_32x32x16_bf16(aK, bQ[kk], sT[s], 0, 0, 0);
            }
          }
        }
        __builtin_amdgcn_s_setprio(0);

        // masks + row-max over active sub-tiles (4 parallel accumulators)
        float a0 = -INFINITY, a1 = -INFINITY, a2 = -INFINITY, a3 = -INFINITY;
#pragma unroll
        for (int s = 0; s < 4; ++s) {
          if (s < nact) {
            int diag_s = causal && (kv0 + s * 32 + 31 > qw);  // wave-uniform
            if (diag_s || has_mask) {
#pragma unroll
              for (int r = 0; r < 16; ++r) {
                int kvloc = s * 32 + (r & 3) + 8 * (r >> 2) + 4 * hi;
                float sv = sT[s][r];
                if (has_mask) sv += bias_lds[cur][kvloc];
                if (diag_s && (kv0 + kvloc) > qrow) sv = -1e30f;
                sT[s][r] = sv;
              }
            }
#pragma unroll
            for (int r = 0; r < 16; r += 4) {
              a0 = fmaxf(a0, sT[s][r + 0]); a1 = fmaxf(a1, sT[s][r + 1]);
              a2 = fmaxf(a2, sT[s][r + 2]); a3 = fmaxf(a3, sT[s][r + 3]);
            }
          }
        }
        float mx = max3f(max3f(a0, a1, a2), a3, -3.0e30f);
        mx = fmaxf(mx, __shfl_xor(mx, 32));

        // T13 defer-rescale
        if (!__all(mx - m_run <= 8.0f)) {
          float mnew = fmaxf(m_run, mx);
          float sc_o = exp2f(m_run - mnew);
          m_run = mnew;
          l_run *= sc_o;
          red[w][l31] = sc_o;
#pragma unroll
          for (int r = 0; r < 16; ++r) {
            float f = red[w][(r & 3) + 8 * (r >> 2) + 4 * hi];
            accO[0][r] *= f;
            accO[1][r] *= f;
          }
        }

        // exp + 4-way parallel partial sums (active sub-tiles only)
        float s0acc = 0.f, s1acc = 0.f, s2acc = 0.f, s3acc = 0.f;
#pragma unroll
        for (int s = 0; s < 4; ++s) {
          if (s < nact) {
#pragma unroll
            for (int r = 0; r < 16; r += 4) {
              float p0 = exp2f(sT[s][r + 0] - m_run);
              float p1 = exp2f(sT[s][r + 1] - m_run);
              float p2 = exp2f(sT[s][r + 2] - m_run);
              float p3 = exp2f(sT[s][r + 3] - m_run);
              sT[s][r + 0] = p0; sT[s][r + 1] = p1;
              sT[s][r + 2] = p2; sT[s][r + 3] = p3;
              s0acc += p0; s1acc += p1; s2acc += p2; s3acc += p3;
            }
          }
        }
        float ls = (s0acc + s1acc) + (s2acc + s3acc);
        ls += __shfl_xor(ls, 32);
        l_run += ls;

        // P -> A-frag via cvt_pk + permlane32_swap (T12) + PV
#pragma unroll
        for (int c = 0; c < 8; ++c) {
          if ((c >> 1) < nact) {
            int s = c >> 1, kk = c & 1;
            unsigned int x0 = pk2(sT[s][8 * kk + 0], sT[s][8 * kk + 1]);
            unsigned int y0 = pk2(sT[s][8 * kk + 2], sT[s][8 * kk + 3]);
            unsigned int x1 = pk2(sT[s][8 * kk + 4], sT[s][8 * kk + 5]);
            unsigned int y1 = pk2(sT[s][8 * kk + 6], sT[s][8 * kk + 7]);
            asm("v_permlane32_swap_b32 %0, %1" : "+v"(x0), "+v"(x1));
            asm("v_permlane32_swap_b32 %0, %1" : "+v"(y0), "+v"(y1));
            union { unsigned int u[4]; s16x8 v; } pf;
            pf.u[0] = x0;
            pf.u[1] = y0;
            pf.u[2] = x1;
            pf.u[3] = y1;
            __builtin_amdgcn_s_setprio(1);
#pragma unroll
            for (int dt = 0; dt < 2; ++dt) {
              s16x8 vf = *(const s16x8*)(vbase + (dt * 32 + l31) * 256 +
                                         ((c * 32 + hi * 16) ^ (l7 << 4)));
              accO[dt] = __builtin_amdgcn_mfma_f32_32x32x16_bf16(pf.v, vf, accO[dt], 0, 0, 0);
            }
            __builtin_amdgcn_s_setprio(0);
          }
        }
      }

      // write next tile into the other buffer, then ONE barrier (both hazards)
      if (it + 1 < nT) {
        WRITE_KV(nxt);
        if (has_mask && tid < 128) bias_lds[nxt][tid] = mp[kv0 + 128 + tid] ? -1e30f : 0.0f;
      }
      __syncthreads();
    }

    // epilogue
    red[w][l31] = 1.0f / l_run;
#pragma unroll
    for (int r = 0; r < 16; ++r) {
      int R = (r & 3) + 8 * (r >> 2) + 4 * hi;
      float f = red[w][R];
      int qg = qw + R;
      size_t base = ((size_t)b * TQ_ + qg) * DM_ + h * DH_ + l31;
      Ob[base] = f2bf(accO[0][r] * f);
      Ob[base + 32] = f2bf(accO[1][r] * f);
    }
  }
#undef LOAD_KV
#undef WRITE_KV
}

extern "C" void kernel_launch(void* const* d_in, const int* in_sizes, int n_in,
                              void* d_out, int out_size, void* d_ws, size_t ws_size,
                              hipStream_t stream) {
  const float* xq  = (const float*)d_in[0];
  const float* xkv = (const float*)d_in[1];
  const unsigned char* mask = (const unsigned char*)d_in[2];
  const float* Wq  = (const float*)d_in[3];
  const float* bq  = (const float*)d_in[4];
  const float* Wkv = (const float*)d_in[5];
  const float* bkv = (const float*)d_in[6];
  const float* Wo  = (const float*)d_in[7];
  const float* bo  = (const float*)d_in[8];
  const int* cflag = (const int*)d_in[9];
  float* out = (float*)d_out;

  char* ws = (char*)d_ws;
  unsigned short* WqT  = (unsigned short*)(ws);                       // 2 MiB
  unsigned short* WkvT = (unsigned short*)(ws + ((size_t)2 << 20));   // 4 MiB
  unsigned short* WoT  = (unsigned short*)(ws + ((size_t)6 << 20));   // 2 MiB
  unsigned short* Qb   = (unsigned short*)(ws + ((size_t)8 << 20));   // [B,H,TQ,64]
  unsigned short* Kb   = (unsigned short*)(ws + ((size_t)24 << 20));  // [B,H,TKV,64]
  unsigned short* Vb   = (unsigned short*)(ws + ((size_t)40 << 20));  // [B,H,64,TKV]
  unsigned short* Xr   = (unsigned short*)(ws + ((size_t)56 << 20));  // Aq -> Akv -> Ob
  unsigned short* Ob   = Xr;

  // fused prep: 3 weight transposes + xq cast
  k_prep<<<3072, 256, 0, stream>>>(Wq, WqT, Wkv, WkvT, Wo, WoT, xq, Xr, B_ * TQ_ * DM_ / 4);

  k_gemm8<0, 128><<<dim3(8, 32), 512, 0, stream>>>(Xr, WqT, bq, SC_FOLD, Qb, nullptr, nullptr, 1024);

  k_cast_bf16<<<2048, 256, 0, stream>>>(xkv, Xr, B_ * TKV_ * DM_ / 4);
  k_gemm8<1, 256><<<dim3(8, 32), 512, 0, stream>>>(Xr, WkvT, bkv, 1.0f, Kb, Vb, nullptr, 1024);

  k_attn<<<dim3(8, B_ * H_), 256, 0, stream>>>(Qb, Kb, Vb, mask, cflag, Ob);

  k_gemm8<2, 128><<<dim3(8, 32), 512, 0, stream>>>(Ob, WoT, bo, 1.0f, nullptr, nullptr, out, 1024);
}

// Round 18
// 183.071 us; speedup vs baseline: 1.9399x; 1.0311x over previous
//
#include <hip/hip_runtime.h>
#include <hip/hip_bf16.h>

#define B_   4
#define TQ_  2048
#define TKV_ 2048
#define DM_  1024
#define H_   16
#define DH_  64

// 1/sqrt(DK) * log2(e), folded into Wq/bq so attention exp2 needs no scaling
#define SC_FOLD 0.18033688011112042f

using f32x4  = __attribute__((ext_vector_type(4))) float;
using f32x16 = __attribute__((ext_vector_type(16))) float;
using s16x8  = __attribute__((ext_vector_type(8))) short;

static __device__ __forceinline__ unsigned short f2bf(float f) {
  union { float f; unsigned int u; } v; v.f = f;
  unsigned int r = v.u + 0x7FFFu + ((v.u >> 16) & 1u);
  return (unsigned short)(r >> 16);
}
// packed f32 pair -> 2xbf16 (RNE) in one instruction
static __device__ __forceinline__ unsigned int pk2(float a, float b) {
  unsigned int r;
  asm("v_cvt_pk_bf16_f32 %0, %1, %2" : "=v"(r) : "v"(a), "v"(b));
  return r;
}
static __device__ __forceinline__ float max3f(float a, float b, float c) {
  float r;
  asm("v_max3_f32 %0, %1, %2, %3" : "=v"(r) : "v"(a), "v"(b), "v"(c));
  return r;
}

// async global->LDS, 16B per lane; LDS dest is wave-uniform base + lane*16
#define GL16(g, l)                                                          \
  __builtin_amdgcn_global_load_lds(                                         \
      (const __attribute__((address_space(1))) unsigned int*)(g),           \
      (__attribute__((address_space(3))) unsigned int*)(l), 16, 0, 0)

// ---------------- device helpers: transpose tile + cast loop ----------------
static __device__ __forceinline__ void transpose_tile(
    const float* W, unsigned short* WT, int K, int N, int n0, int k0, float scale,
    float (*t)[65]) {
  int tx = threadIdx.x & 63, ty = threadIdx.x >> 6;
#pragma unroll
  for (int i = 0; i < 64; i += 4)
    t[ty + i][tx] = W[(size_t)(k0 + ty + i) * N + n0 + tx];
  __syncthreads();
#pragma unroll
  for (int i = 0; i < 64; i += 4)
    WT[(size_t)(n0 + ty + i) * K + k0 + tx] = f2bf(t[tx][ty + i] * scale);
}
static __device__ __forceinline__ void cast_gs(
    const float* in, unsigned short* out, int n4, int cb, int ncb) {
  for (int i = cb * 256 + threadIdx.x; i < n4; i += ncb * 256) {
    f32x4 v = *(const f32x4*)(in + (size_t)i * 4);
    unsigned long long u = (unsigned long long)pk2(v[0], v[1]) |
                           ((unsigned long long)pk2(v[2], v[3]) << 32);
    *(unsigned long long*)(out + (size_t)i * 4) = u;
  }
}

// ---------------- fused prep ----------------
// blocks [0,256)=Wq^T, [256,768)=Wkv^T, [768,1024)=Wo^T, [1024,3072)=cast xq,
// [3072,5120)=cast xkv (only when launched with 5120 blocks)
__global__ __launch_bounds__(256) void k_prep(
    const float* __restrict__ Wq, unsigned short* __restrict__ WqT,
    const float* __restrict__ Wkv, unsigned short* __restrict__ WkvT,
    const float* __restrict__ Wo, unsigned short* __restrict__ WoT,
    const float* __restrict__ xq, unsigned short* __restrict__ Aq,
    const float* __restrict__ xkv, unsigned short* __restrict__ Akv, int n4) {
  int bid = blockIdx.x;
  if (bid >= 3072) { cast_gs(xkv, Akv, n4, bid - 3072, 2048); return; }
  if (bid >= 1024) { cast_gs(xq, Aq, n4, bid - 1024, 2048); return; }
  __shared__ float t[64][65];
  if (bid < 256) {
    transpose_tile(Wq, WqT, 1024, 1024, (bid & 15) * 64, (bid >> 4) * 64, SC_FOLD, t);
  } else if (bid < 768) {
    int b2 = bid - 256;
    transpose_tile(Wkv, WkvT, 1024, 2048, (b2 & 31) * 64, (b2 >> 5) * 64, 1.0f, t);
  } else {
    int b2 = bid - 768;
    transpose_tile(Wo, WoT, 1024, 1024, (b2 & 15) * 64, (b2 >> 4) * 64, 1.0f, t);
  }
}

// ---------------- standalone cast (fallback path) ----------------
__global__ __launch_bounds__(256) void k_cast_bf16(
    const float* __restrict__ in, unsigned short* __restrict__ out, int n4) {
  cast_gs(in, out, n4, blockIdx.x, gridDim.x);
}

// ---------------- GEMM body, 8-phase 256-row tile (T1..T5) ----------------
template <int MODE, int BN>
static __device__ __forceinline__ void gemm_body(
    const unsigned short* __restrict__ A, const unsigned short* __restrict__ BT,
    const float* __restrict__ bias, float bscale, unsigned short* __restrict__ out_a,
    unsigned short* __restrict__ out_b, float* __restrict__ out_f, int Kd,
    int bx, int by, unsigned short* As, unsigned short* Bs) {
  constexpr int NI = BN / 64;
  constexpr int NH = NI / 2;
  const int tid = threadIdx.x, lane = tid & 63, w = tid >> 6;
  const int wm = w >> 2, wn = w & 3;
  int m0 = by * 256, n0 = bx * BN;

  const int strow = tid >> 3;
  const int sx = ((tid & 7) << 4) ^ ((strow & 7) << 4);
  const char* gA = (const char*)(A + (size_t)(m0 + strow) * Kd) + sx;
  const char* gB = (const char*)(BT + (size_t)(n0 + strow) * Kd) + sx;
  char* lA = (char*)As;
  char* lB = (char*)Bs;

#define ST_A(bf, c, k0) \
  GL16(gA + ((size_t)(c) * 64 * Kd + (size_t)(k0)) * 2, lA + (bf) * 32768 + (c) * 8192 + tid * 16)
#define ST_B(bf, c, k0) \
  GL16(gB + ((size_t)(c) * 64 * Kd + (size_t)(k0)) * 2, lB + (bf) * (BN * 128) + (c) * 8192 + tid * 16)

  f32x4 acc[8][NI];
#pragma unroll
  for (int i = 0; i < 8; ++i)
#pragma unroll
    for (int j = 0; j < NI; ++j) acc[i][j] = (f32x4){0.f, 0.f, 0.f, 0.f};

  s16x8 afr[4][2], bfr[NI][2];
  const int arow = wm * 128 + (lane & 15);
  const int brow = wn * (NI * 16) + (lane & 15);
  const int fcol = (lane >> 4) * 16;

#define RD_A(bf, r) (*(const s16x8*)(lA + (bf) * 32768 + (r) * 128 + ((fcol + _kk * 64) ^ (((r) & 7) << 4))))
#define RD_B(bf, r) (*(const s16x8*)(lB + (bf) * (BN * 128) + (r) * 128 + ((fcol + _kk * 64) ^ (((r) & 7) << 4))))

  const int nT = Kd >> 6;

  ST_B(0, 0, 0); ST_B(0, 1, 0);
  if (BN == 256) { ST_B(0, 2, 0); ST_B(0, 3, 0); }
  ST_A(0, 0, 0); ST_A(0, 2, 0);
  ST_A(0, 1, 0); ST_A(0, 3, 0);
  asm volatile("s_waitcnt vmcnt(2)" ::: "memory");
  __builtin_amdgcn_s_barrier();

#pragma unroll 1
  for (int t = 0; t < nT; ++t) {
    const int cur = t & 1, nxt = cur ^ 1;
    const int k1 = (t + 1) << 6;
    const bool st = (t + 1 < nT);

#pragma unroll
    for (int mi = 0; mi < 4; ++mi)
#pragma unroll
      for (int _kk = 0; _kk < 2; ++_kk) afr[mi][_kk] = RD_A(cur, arow + mi * 16);
#pragma unroll
    for (int ni = 0; ni < NH; ++ni)
#pragma unroll
      for (int _kk = 0; _kk < 2; ++_kk) bfr[ni][_kk] = RD_B(cur, brow + ni * 16);
    if (st) { ST_B(nxt, 0, k1); ST_B(nxt, 1, k1); }
    __builtin_amdgcn_s_barrier();
    __builtin_amdgcn_s_setprio(1);
#pragma unroll
    for (int mi = 0; mi < 4; ++mi)
#pragma unroll
      for (int ni = 0; ni < NH; ++ni)
#pragma unroll
        for (int kk = 0; kk < 2; ++kk)
          acc[mi][ni] = __builtin_amdgcn_mfma_f32_16x16x32_bf16(afr[mi][kk], bfr[ni][kk], acc[mi][ni], 0, 0, 0);
    __builtin_amdgcn_s_setprio(0);
    __builtin_amdgcn_s_barrier();

#pragma unroll
    for (int ni = NH; ni < NI; ++ni)
#pragma unroll
      for (int _kk = 0; _kk < 2; ++_kk) bfr[ni][_kk] = RD_B(cur, brow + ni * 16);
    if (st) {
      if (BN == 256) { ST_B(nxt, 2, k1); ST_B(nxt, 3, k1); }
      else           { ST_A(nxt, 0, k1); ST_A(nxt, 2, k1); }
    }
    if (st) asm volatile("s_waitcnt vmcnt(4)" ::: "memory");
    else    asm volatile("s_waitcnt vmcnt(0)" ::: "memory");
    __builtin_amdgcn_s_barrier();
    __builtin_amdgcn_s_setprio(1);
#pragma unroll
    for (int mi = 0; mi < 4; ++mi)
#pragma unroll
      for (int ni = NH; ni < NI; ++ni)
#pragma unroll
        for (int kk = 0; kk < 2; ++kk)
          acc[mi][ni] = __builtin_amdgcn_mfma_f32_16x16x32_bf16(afr[mi][kk], bfr[ni][kk], acc[mi][ni], 0, 0, 0);
    __builtin_amdgcn_s_setprio(0);
    __builtin_amdgcn_s_barrier();

#pragma unroll
    for (int mi = 0; mi < 4; ++mi)
#pragma unroll
      for (int _kk = 0; _kk < 2; ++_kk) afr[mi][_kk] = RD_A(cur, arow + (mi + 4) * 16);
    if (st) {
      if (BN == 256) { ST_A(nxt, 0, k1); ST_A(nxt, 2, k1); }
      else           { ST_A(nxt, 1, k1); ST_A(nxt, 3, k1); }
    }
    __builtin_amdgcn_s_barrier();
    __builtin_amdgcn_s_setprio(1);
#pragma unroll
    for (int mi = 0; mi < 4; ++mi)
#pragma unroll
      for (int ni = 0; ni < NH; ++ni)
#pragma unroll
        for (int kk = 0; kk < 2; ++kk)
          acc[mi + 4][ni] = __builtin_amdgcn_mfma_f32_16x16x32_bf16(afr[mi][kk], bfr[ni][kk], acc[mi + 4][ni], 0, 0, 0);
    __builtin_amdgcn_s_setprio(0);
    __builtin_amdgcn_s_barrier();

    if (st && BN == 256) { ST_A(nxt, 1, k1); ST_A(nxt, 3, k1); }
    asm volatile("s_waitcnt vmcnt(2)" ::: "memory");
    __builtin_amdgcn_s_barrier();
    __builtin_amdgcn_s_setprio(1);
#pragma unroll
    for (int mi = 0; mi < 4; ++mi)
#pragma unroll
      for (int ni = NH; ni < NI; ++ni)
#pragma unroll
        for (int kk = 0; kk < 2; ++kk)
          acc[mi + 4][ni] = __builtin_amdgcn_mfma_f32_16x16x32_bf16(afr[mi][kk], bfr[ni][kk], acc[mi + 4][ni], 0, 0, 0);
    __builtin_amdgcn_s_setprio(0);
    __builtin_amdgcn_s_barrier();
  }

#pragma unroll
  for (int mi = 0; mi < 8; ++mi) {
#pragma unroll
    for (int ni = 0; ni < NI; ++ni) {
      int col = n0 + wn * (NI * 16) + ni * 16 + (lane & 15);
      int rbase = m0 + wm * 128 + mi * 16 + (lane >> 4) * 4;
      float bv = bias[col] * bscale;
      if (MODE == 1 && col >= H_ * DH_) {
        int c2 = col - H_ * DH_;
        int h = c2 >> 6, d = c2 & 63;
        int b = rbase >> 11, tt = rbase & 2047;
        union { unsigned short h4[4]; unsigned long long u; } p;
#pragma unroll
        for (int r = 0; r < 4; ++r) p.h4[r] = f2bf(acc[mi][ni][r] + bv);
        *(unsigned long long*)(out_b + ((((size_t)b * H_ + h) * DH_ + d) * TKV_ + tt)) = p.u;
      } else {
#pragma unroll
        for (int r = 0; r < 4; ++r) {
          float v = acc[mi][ni][r] + bv;
          int m = rbase + r;
          if (MODE == 0) {
            int b = m >> 11, tt = m & 2047;
            int h = col >> 6, d = col & 63;
            out_a[(((size_t)b * H_ + h) * TQ_ + tt) * DH_ + d] = f2bf(v);
          } else if (MODE == 1) {
            int b = m >> 11, tt = m & 2047;
            int h = col >> 6, d = col & 63;
            out_a[(((size_t)b * H_ + h) * TKV_ + tt) * DH_ + d] = f2bf(v);
          } else {
            out_f[(size_t)m * DM_ + col] = v;
          }
        }
      }
    }
  }
#undef ST_A
#undef ST_B
#undef RD_A
#undef RD_B
}

// standalone GEMM (fallback path + out-proj)
template <int MODE, int BN>
__global__ __launch_bounds__(512, 2) void k_gemm8(
    const unsigned short* __restrict__ A, const unsigned short* __restrict__ BT,
    const float* __restrict__ bias, float bscale, unsigned short* __restrict__ out_a,
    unsigned short* __restrict__ out_b, float* __restrict__ out_f, int Kd) {
  __shared__ __align__(16) unsigned short As[2 * 256 * 64];
  __shared__ __align__(16) unsigned short Bs[2 * BN * 64];
  int nwg = gridDim.x * gridDim.y;
  int bid = blockIdx.y * gridDim.x + blockIdx.x;
  int cpx = nwg >> 3;
  int sw = (bid & 7) * cpx + (bid >> 3);
  int bx = sw % gridDim.x, by = sw / gridDim.x;
  gemm_body<MODE, BN>(A, BT, bias, bscale, out_a, out_b, out_f, Kd, bx, by, As, Bs);
}

// merged Q-proj + KV-proj: grid (8,64); by<32 -> Q (BN=128), by>=32 -> KV (BN=256)
__global__ __launch_bounds__(512, 2) void k_gemm_qkv(
    const unsigned short* __restrict__ Aq, const unsigned short* __restrict__ WqT,
    const float* __restrict__ bq,
    const unsigned short* __restrict__ Akv, const unsigned short* __restrict__ WkvT,
    const float* __restrict__ bkv,
    unsigned short* __restrict__ Qb, unsigned short* __restrict__ Kb,
    unsigned short* __restrict__ Vb) {
  __shared__ __align__(16) unsigned short As[2 * 256 * 64];
  __shared__ __align__(16) unsigned short Bs[2 * 256 * 64];
  bool isQ = blockIdx.y < 32;
  int lby = isQ ? blockIdx.y : (blockIdx.y - 32);
  int bid = lby * 8 + blockIdx.x;           // local bid within the 256-wg half
  int sw = (bid & 7) * 32 + (bid >> 3);     // per-half XCD swizzle (cpx = 32)
  int bx = sw & 7, by = sw >> 3;
  if (isQ)
    gemm_body<0, 128>(Aq, WqT, bq, SC_FOLD, Qb, nullptr, nullptr, 1024, bx, by, As, Bs);
  else
    gemm_body<1, 256>(Akv, WkvT, bkv, 1.0f, Kb, Vb, nullptr, 1024, bx, by, As, Bs);
}

// ---------------- flash attention (R13-verified best, unchanged) ----------------
__global__ __launch_bounds__(256, 2) void k_attn(
    const unsigned short* __restrict__ Qb, const unsigned short* __restrict__ Kb,
    const unsigned short* __restrict__ Vtb, const unsigned char* __restrict__ mask,
    const int* __restrict__ cflag, unsigned short* __restrict__ Ob) {
  __shared__ __align__(16) unsigned short Kt[2][128 * 64];  // [buf][kv][d], XOR-swizzled
  __shared__ __align__(16) unsigned short Vt[2][64 * 128];  // [buf][d][kv], XOR-swizzled
  __shared__ float bias_lds[2][128];
  __shared__ float red[4][32];
  __shared__ int s_any;

  int bid = blockIdx.y * gridDim.x + blockIdx.x;
  int r8 = bid & 7, q8 = bid >> 3;
  int bh = r8 * 8 + (q8 >> 3);
  int bx = q8 & 7;

  int b = bh >> 4, h = bh & 15;
  int tid = threadIdx.x, lane = tid & 63, w = tid >> 6;
  int hi = lane >> 5, l31 = lane & 31, l7 = lane & 7;
  const unsigned short* Qp = Qb + (size_t)bh * TQ_ * DH_;
  const char* Kp = (const char*)(Kb + (size_t)bh * TKV_ * DH_);
  const char* Vp = (const char*)(Vtb + (size_t)bh * DH_ * TKV_);
  const unsigned char* mp = mask + (size_t)b * TKV_;
  int causal = cflag[0];

  int st_r4 = tid >> 2;
  int st_c4 = (tid & 3) * 16;
  s16x8 pKr[4], pVr[4];

#define LOAD_KV(kv0)                                                          \
  {                                                                           \
    _Pragma("unroll")                                                         \
    for (int p = 0; p < 4; ++p) {                                             \
      int krow = (p >> 1) * 64 + st_r4;                                       \
      int kx = st_c4 + (p & 1) * 64;                                          \
      pKr[p] = *(const s16x8*)(Kp + ((size_t)((kv0) + krow) * 128 + kx));     \
      int vx = st_c4 + p * 64;                                                \
      pVr[p] = *(const s16x8*)(Vp + (((size_t)st_r4 * TKV_ + (kv0)) * 2 + vx)); \
    }                                                                         \
  }
#define WRITE_KV(bufi)                                                        \
  {                                                                           \
    char* kb_ = (char*)&Kt[bufi][0];                                          \
    char* vb_ = (char*)&Vt[bufi][0];                                          \
    _Pragma("unroll")                                                         \
    for (int p = 0; p < 4; ++p) {                                             \
      int krow = (p >> 1) * 64 + st_r4;                                       \
      int kx = st_c4 + (p & 1) * 64;                                          \
      *(s16x8*)(kb_ + krow * 128 + (kx ^ ((st_r4 & 7) << 4))) = pKr[p];       \
      int vx = st_c4 + p * 64;                                                \
      *(s16x8*)(vb_ + st_r4 * 256 + (vx ^ ((st_r4 & 7) << 4))) = pVr[p];      \
    }                                                                         \
  }

  if (tid == 0) s_any = 0;
  __syncthreads();
  {
    int any = 0;
    for (int i = tid; i < TKV_; i += 256) any |= mp[i];
    if (any) s_any = 1;
  }
  __syncthreads();
  const int has_mask = s_any;

#pragma unroll 1
  for (int pass = 0; pass < 2; ++pass) {
    int qb = (pass ? (15 - bx) : bx) * 128;
    int qw = qb + w * 32;
    int qrow = qw + l31;

    s16x8 bQ[4];
#pragma unroll
    for (int kk = 0; kk < 4; ++kk)
      bQ[kk] = *(const s16x8*)(Qp + (size_t)qrow * DH_ + kk * 16 + hi * 8);

    f32x16 accO[2];
#pragma unroll
    for (int i = 0; i < 16; ++i) { accO[0][i] = 0.f; accO[1][i] = 0.f; }
    float m_run = -INFINITY, l_run = 0.f;

    int nT = (causal ? (qb + 128) : TKV_) >> 7;

    LOAD_KV(0);
    WRITE_KV(0);
    if (has_mask && tid < 128) bias_lds[0][tid] = mp[tid] ? -1e30f : 0.0f;
    __syncthreads();

#pragma unroll 1
    for (int it = 0; it < nT; ++it) {
      int kv0 = it << 7;
      int cur = it & 1, nxt = cur ^ 1;
      if (it + 1 < nT) LOAD_KV(kv0 + 128);

      char* kbase = (char*)&Kt[cur][0];
      char* vbase = (char*)&Vt[cur][0];

      int nact = 4;
      if (causal) {
        int rem = qw + 31 - kv0;
        nact = rem < 0 ? 0 : ((rem >> 5) + 1);
        if (nact > 4) nact = 4;
      }

      if (nact > 0) {
        f32x16 sT[4];
        __builtin_amdgcn_s_setprio(1);
#pragma unroll
        for (int s = 0; s < 4; ++s) {
          if (s < nact) {
#pragma unroll
            for (int i = 0; i < 16; ++i) sT[s][i] = 0.f;
#pragma unroll
            for (int kk = 0; kk < 4; ++kk) {
              s16x8 aK = *(const s16x8*)(kbase + (s * 32 + l31) * 128 +
                                         ((kk * 32 + hi * 16) ^ (l7 << 4)));
              sT[s] = __builtin_amdgcn_mfma_f32_32x32x16_bf16(aK, bQ[kk], sT[s], 0, 0, 0);
            }
          }
        }
        __builtin_amdgcn_s_setprio(0);

        float a0 = -INFINITY, a1 = -INFINITY, a2 = -INFINITY, a3 = -INFINITY;
#pragma unroll
        for (int s = 0; s < 4; ++s) {
          if (s < nact) {
            int diag_s = causal && (kv0 + s * 32 + 31 > qw);
            if (diag_s || has_mask) {
#pragma unroll
              for (int r = 0; r < 16; ++r) {
                int kvloc = s * 32 + (r & 3) + 8 * (r >> 2) + 4 * hi;
                float sv = sT[s][r];
                if (has_mask) sv += bias_lds[cur][kvloc];
                if (diag_s && (kv0 + kvloc) > qrow) sv = -1e30f;
                sT[s][r] = sv;
              }
            }
#pragma unroll
            for (int r = 0; r < 16; r += 4) {
              a0 = fmaxf(a0, sT[s][r + 0]); a1 = fmaxf(a1, sT[s][r + 1]);
              a2 = fmaxf(a2, sT[s][r + 2]); a3 = fmaxf(a3, sT[s][r + 3]);
            }
          }
        }
        float mx = max3f(max3f(a0, a1, a2), a3, -3.0e30f);
        mx = fmaxf(mx, __shfl_xor(mx, 32));

        if (!__all(mx - m_run <= 8.0f)) {
          float mnew = fmaxf(m_run, mx);
          float sc_o = exp2f(m_run - mnew);
          m_run = mnew;
          l_run *= sc_o;
          red[w][l31] = sc_o;
#pragma unroll
          for (int r = 0; r < 16; ++r) {
            float f = red[w][(r & 3) + 8 * (r >> 2) + 4 * hi];
            accO[0][r] *= f;
            accO[1][r] *= f;
          }
        }

        float s0acc = 0.f, s1acc = 0.f, s2acc = 0.f, s3acc = 0.f;
#pragma unroll
        for (int s = 0; s < 4; ++s) {
          if (s < nact) {
#pragma unroll
            for (int r = 0; r < 16; r += 4) {
              float p0 = exp2f(sT[s][r + 0] - m_run);
              float p1 = exp2f(sT[s][r + 1] - m_run);
              float p2 = exp2f(sT[s][r + 2] - m_run);
              float p3 = exp2f(sT[s][r + 3] - m_run);
              sT[s][r + 0] = p0; sT[s][r + 1] = p1;
              sT[s][r + 2] = p2; sT[s][r + 3] = p3;
              s0acc += p0; s1acc += p1; s2acc += p2; s3acc += p3;
            }
          }
        }
        float ls = (s0acc + s1acc) + (s2acc + s3acc);
        ls += __shfl_xor(ls, 32);
        l_run += ls;

#pragma unroll
        for (int c = 0; c < 8; ++c) {
          if ((c >> 1) < nact) {
            int s = c >> 1, kk = c & 1;
            unsigned int x0 = pk2(sT[s][8 * kk + 0], sT[s][8 * kk + 1]);
            unsigned int y0 = pk2(sT[s][8 * kk + 2], sT[s][8 * kk + 3]);
            unsigned int x1 = pk2(sT[s][8 * kk + 4], sT[s][8 * kk + 5]);
            unsigned int y1 = pk2(sT[s][8 * kk + 6], sT[s][8 * kk + 7]);
            asm("v_permlane32_swap_b32 %0, %1" : "+v"(x0), "+v"(x1));
            asm("v_permlane32_swap_b32 %0, %1" : "+v"(y0), "+v"(y1));
            union { unsigned int u[4]; s16x8 v; } pf;
            pf.u[0] = x0;
            pf.u[1] = y0;
            pf.u[2] = x1;
            pf.u[3] = y1;
            __builtin_amdgcn_s_setprio(1);
#pragma unroll
            for (int dt = 0; dt < 2; ++dt) {
              s16x8 vf = *(const s16x8*)(vbase + (dt * 32 + l31) * 256 +
                                         ((c * 32 + hi * 16) ^ (l7 << 4)));
              accO[dt] = __builtin_amdgcn_mfma_f32_32x32x16_bf16(pf.v, vf, accO[dt], 0, 0, 0);
            }
            __builtin_amdgcn_s_setprio(0);
          }
        }
      }

      if (it + 1 < nT) {
        WRITE_KV(nxt);
        if (has_mask && tid < 128) bias_lds[nxt][tid] = mp[kv0 + 128 + tid] ? -1e30f : 0.0f;
      }
      __syncthreads();
    }

    red[w][l31] = 1.0f / l_run;
#pragma unroll
    for (int r = 0; r < 16; ++r) {
      int R = (r & 3) + 8 * (r >> 2) + 4 * hi;
      float f = red[w][R];
      int qg = qw + R;
      size_t base = ((size_t)b * TQ_ + qg) * DM_ + h * DH_ + l31;
      Ob[base] = f2bf(accO[0][r] * f);
      Ob[base + 32] = f2bf(accO[1][r] * f);
    }
  }
#undef LOAD_KV
#undef WRITE_KV
}

extern "C" void kernel_launch(void* const* d_in, const int* in_sizes, int n_in,
                              void* d_out, int out_size, void* d_ws, size_t ws_size,
                              hipStream_t stream) {
  const float* xq  = (const float*)d_in[0];
  const float* xkv = (const float*)d_in[1];
  const unsigned char* mask = (const unsigned char*)d_in[2];
  const float* Wq  = (const float*)d_in[3];
  const float* bq  = (const float*)d_in[4];
  const float* Wkv = (const float*)d_in[5];
  const float* bkv = (const float*)d_in[6];
  const float* Wo  = (const float*)d_in[7];
  const float* bo  = (const float*)d_in[8];
  const int* cflag = (const int*)d_in[9];
  float* out = (float*)d_out;

  char* ws = (char*)d_ws;
  unsigned short* WqT  = (unsigned short*)(ws);                       // 2 MiB
  unsigned short* WkvT = (unsigned short*)(ws + ((size_t)2 << 20));   // 4 MiB
  unsigned short* WoT  = (unsigned short*)(ws + ((size_t)6 << 20));   // 2 MiB
  unsigned short* Qb   = (unsigned short*)(ws + ((size_t)8 << 20));   // [B,H,TQ,64]
  unsigned short* Kb   = (unsigned short*)(ws + ((size_t)24 << 20));  // [B,H,TKV,64]
  unsigned short* Vb   = (unsigned short*)(ws + ((size_t)40 << 20));  // [B,H,64,TKV]
  unsigned short* Xr   = (unsigned short*)(ws + ((size_t)56 << 20));  // Aq / Ob
  unsigned short* Ob   = Xr;
  const int n4 = B_ * TQ_ * DM_ / 4;

  if (ws_size >= ((size_t)88 << 20)) {
    // expanded layout: Akv in its own region; 4-launch chain
    unsigned short* Akv = (unsigned short*)(ws + ((size_t)72 << 20));
    k_prep<<<5120, 256, 0, stream>>>(Wq, WqT, Wkv, WkvT, Wo, WoT, xq, Xr, xkv, Akv, n4);
    k_gemm_qkv<<<dim3(8, 64), 512, 0, stream>>>(Xr, WqT, bq, Akv, WkvT, bkv, Qb, Kb, Vb);
    k_attn<<<dim3(8, B_ * H_), 256, 0, stream>>>(Qb, Kb, Vb, mask, cflag, Ob);
    k_gemm8<2, 128><<<dim3(8, 32), 512, 0, stream>>>(Ob, WoT, bo, 1.0f, nullptr, nullptr, out, 1024);
  } else {
    // fallback: R16-proven 6-launch chain within 72 MiB
    k_prep<<<3072, 256, 0, stream>>>(Wq, WqT, Wkv, WkvT, Wo, WoT, xq, Xr, xkv, nullptr, n4);
    k_gemm8<0, 128><<<dim3(8, 32), 512, 0, stream>>>(Xr, WqT, bq, SC_FOLD, Qb, nullptr, nullptr, 1024);
    k_cast_bf16<<<2048, 256, 0, stream>>>(xkv, Xr, n4);
    k_gemm8<1, 256><<<dim3(8, 32), 512, 0, stream>>>(Xr, WkvT, bkv, 1.0f, Kb, Vb, nullptr, 1024);
    k_attn<<<dim3(8, B_ * H_), 256, 0, stream>>>(Qb, Kb, Vb, mask, cflag, Ob);
    k_gemm8<2, 128><<<dim3(8, 32), 512, 0, stream>>>(Ob, WoT, bo, 1.0f, nullptr, nullptr, out, 1024);
  }
}